// Round 2
// baseline (321.645 us; speedup 1.0000x reference)
//
#include <hip/hip_runtime.h>
#include <hip/hip_fp16.h>

// Problem constants (from the reference file)
#define N_NODES 50000
#define N_EDGES 800000
#define F_IN_D  128
#define H_DIM   256
#define L_DIM   64
#define G_NUM   500

typedef unsigned int   u32;
typedef unsigned short u16;
typedef unsigned char  u8;
typedef __attribute__((ext_vector_type(8))) short short8;
typedef __attribute__((ext_vector_type(4))) float f32x4;
typedef __attribute__((ext_vector_type(2))) float f32x2;

static __device__ __forceinline__ float bf2f(u16 u) {
    union { u32 i; float f; } x; x.i = ((u32)u) << 16; return x.f;
}
static __device__ __forceinline__ u16 f2bf(float f) {
    union { float f; u32 i; } x; x.f = f;
    u32 r = (x.i + 0x7fffu + ((x.i >> 16) & 1u)) >> 16;
    return (u16)r;
}
// csr entry: src node in low 16 bits (N_NODES < 65536), fp16(dinv[src]) in high 16
static __device__ __forceinline__ float edge_w(u32 e) {
    return __half2float(__ushort_as_half((u16)(e >> 16)));
}

// pack two bf16-pairs (4 values) into 4 fp8 e4m3 bytes via HW converter
static __device__ __forceinline__ u32 pack4_fp8(u32 a, u32 b) {
    u32 w = __builtin_amdgcn_cvt_pk_fp8_f32(bf2f((u16)(a & 0xffff)),
                                            bf2f((u16)(a >> 16)), 0, false);
    w = __builtin_amdgcn_cvt_pk_fp8_f32(bf2f((u16)(b & 0xffff)),
                                        bf2f((u16)(b >> 16)), w, true);
    return w;
}

// B-swizzle address (in u16 units): fragment layout for mfma_16x16x32_bf16.
static __device__ __forceinline__ u32 bswz_idx(int n, int k, int plane, int KS) {
    int n0g = n >> 6, nt = (n >> 4) & 3, lr = n & 15;
    int k0i = k >> 5, ks = k & 31, lq = ks >> 3, j = ks & 7;
    return ((u32)((((n0g * KS + k0i) * 2 + plane) * 4 + nt) * 64 + lq * 16 + lr)) * 8 + j;
}

// ---------------------------------------------------------------------------
// Fused preprocessing: degree count + batch bounds + all dtype conversions.
// ---------------------------------------------------------------------------
#define NXQ (N_NODES * F_IN_D / 4)          // 1,600,000
#define NW1 (F_IN_D * H_DIM)                // 32,768
#define NW2 (H_DIM * H_DIM)                 // 65,536
#define NB_COUNT ((N_EDGES + 255) / 256)            // 3125
#define NB_SCAN  ((N_NODES + 255) / 256)            // 196
#define NB_CONV  ((NXQ + NW1 + NW2 + 255) / 256)    // 6634

__global__ void prep_kernel(const int* __restrict__ dst, int* __restrict__ hist,
                            const int* __restrict__ batch, int* __restrict__ goff,
                            const float* __restrict__ x, u16* __restrict__ xb,
                            const float* __restrict__ W1, u16* __restrict__ w1swz,
                            const float* __restrict__ W2, u16* __restrict__ w2swz) {
    int b = blockIdx.x;
    if (b < NB_COUNT) {
        int i = b * 256 + threadIdx.x;
        if (i < N_EDGES) atomicAdd(&hist[dst[i]], 1);
    } else if (b < NB_COUNT + NB_SCAN) {
        int i = (b - NB_COUNT) * 256 + threadIdx.x;
        if (i >= N_NODES) return;
        int v = batch[i];
        if (i == 0) {
            for (int g = 0; g <= v; ++g) goff[g] = 0;
        } else {
            int p = batch[i - 1];
            for (int g = p + 1; g <= v; ++g) goff[g] = i;
        }
        if (i == N_NODES - 1) {
            for (int g = v + 1; g <= G_NUM; ++g) goff[g] = N_NODES;
        }
    } else {
        int i = (b - NB_COUNT - NB_SCAN) * 256 + threadIdx.x;
        if (i < NXQ) {
            float4 v = *(const float4*)&x[(size_t)i * 4];
            ushort4 o;
            o.x = f2bf(v.x); o.y = f2bf(v.y); o.z = f2bf(v.z); o.w = f2bf(v.w);
            *(ushort4*)&xb[(size_t)i * 4] = o;
        } else if (i < NXQ + NW1) {
            int idx = i - NXQ;
            int k = idx >> 8, n = idx & 255;
            float w = W1[idx];
            u16 h = f2bf(w);
            w1swz[bswz_idx(n, k, 0, F_IN_D / 32)] = h;
            w1swz[bswz_idx(n, k, 1, F_IN_D / 32)] = f2bf(w - bf2f(h));
        } else if (i < NXQ + NW1 + NW2) {
            int idx = i - NXQ - NW1;
            int k = idx >> 8, n = idx & 255;
            float w = W2[idx];
            u16 h = f2bf(w);
            w2swz[bswz_idx(n, k, 0, H_DIM / 32)] = h;
            w2swz[bswz_idx(n, k, 1, H_DIM / 32)] = f2bf(w - bf2f(h));
        }
    }
}

// exclusive scan of hist (chunk=256) + fused dinv computation
__global__ void scan_chunk_kernel(const int* __restrict__ in, int* __restrict__ excl,
                                  int* __restrict__ partials, float* __restrict__ dinv, int n) {
    __shared__ int sm[256];
    int t = threadIdx.x;
    int i = blockIdx.x * 256 + t;
    int v = (i < n) ? in[i] : 0;
    sm[t] = v; __syncthreads();
    for (int off = 1; off < 256; off <<= 1) {
        int x = (t >= off) ? sm[t - off] : 0;
        __syncthreads();
        sm[t] += x;
        __syncthreads();
    }
    if (i < n) {
        excl[i] = sm[t] - v;
        dinv[i] = 1.0f / sqrtf((float)(v + 1));   // +1 self loop
    }
    if (t == 255) partials[blockIdx.x] = sm[255];
}

__global__ void scan_final_kernel(const int* __restrict__ excl, const int* __restrict__ partials,
                                  int* __restrict__ out, int* __restrict__ cursor, int n, int nb) {
    __shared__ int sm[256];
    int t = threadIdx.x;
    int v = (t < nb) ? partials[t] : 0;
    sm[t] = v; __syncthreads();
    for (int off = 1; off < 256; off <<= 1) {
        int x = (t >= off) ? sm[t - off] : 0;
        __syncthreads();
        sm[t] += x;
        __syncthreads();
    }
    int pre = (blockIdx.x > 0) ? sm[blockIdx.x - 1] : 0;   // uniform read
    int i = blockIdx.x * 256 + t;
    if (i < n) {
        int val = excl[i] + pre;
        out[i] = val;
        cursor[i] = val;
    }
    if (blockIdx.x == (unsigned)(nb - 1) && t == 0) out[n] = sm[nb - 1];
}

// ---------------------------------------------------------------------------
// CSR placement. 4B entries (src:16 | fp16(dinv[src]):16) halve the partial-
// line write-back amplification (each csr 64B line is dirtied in ~8 XCD L2s);
// 4 edges/thread overlap the atomic round-trip latency.
// ---------------------------------------------------------------------------
#define EPT 4
#define PLACE_THREADS (N_EDGES / EPT)               // 200,000
#define NB_PLACE ((PLACE_THREADS + 255) / 256)      // 782

__global__ __launch_bounds__(256)
void place_kernel(const int* __restrict__ src, const int* __restrict__ dst,
                  const float* __restrict__ dinv,
                  int* __restrict__ cursor, u32* __restrict__ csr) {
    int t = blockIdx.x * 256 + threadIdx.x;
    if (t >= PLACE_THREADS) return;
    int s[EPT], d[EPT], pos[EPT];
    float di[EPT];
#pragma unroll
    for (int k = 0; k < EPT; ++k) {
        int e = t + k * PLACE_THREADS;
        s[k] = src[e];
        d[k] = dst[e];
    }
#pragma unroll
    for (int k = 0; k < EPT; ++k) di[k] = dinv[s[k]];
#pragma unroll
    for (int k = 0; k < EPT; ++k) pos[k] = atomicAdd(&cursor[d[k]], 1);
#pragma unroll
    for (int k = 0; k < EPT; ++k) {
        u32 h = (u32)__half_as_ushort(__float2half(di[k]));
        csr[pos[k]] = (u32)s[k] | (h << 16);
    }
}

// ---------------------------------------------------------------------------
// GCN aggregation layer 1, bf16 in -> bf16 out. One wave per node.
// ---------------------------------------------------------------------------
__global__ __launch_bounds__(256)
void agg128_kernel(const u16* __restrict__ In, const float* __restrict__ dinv,
                   const int* __restrict__ rp, const u32* __restrict__ csr,
                   u16* __restrict__ Out) {
    int node = blockIdx.x * 4 + (threadIdx.x >> 6);
    int lane = threadIdx.x & 63;
    if (node >= N_NODES) return;
    int c = lane * 2;
    float di = dinv[node];
    int r0 = rp[node], r1 = rp[node + 1];
    u32 sv = *(const u32*)&In[(size_t)node * 128 + c];
    float a0 = di * bf2f((u16)(sv & 0xffff));
    float a1 = di * bf2f((u16)(sv >> 16));
    int j = r0;
    for (; j + 8 <= r1; j += 8) {
        u32 e[8];
        u32 v[8];
#pragma unroll
        for (int q = 0; q < 8; ++q) e[q] = csr[j + q];
#pragma unroll
        for (int q = 0; q < 8; ++q) v[q] = *(const u32*)&In[(size_t)(e[q] & 0xffff) * 128 + c];
#pragma unroll
        for (int q = 0; q < 8; ++q) {
            float w = edge_w(e[q]);
            a0 = fmaf(w, bf2f((u16)(v[q] & 0xffff)), a0);
            a1 = fmaf(w, bf2f((u16)(v[q] >> 16)), a1);
        }
    }
    for (; j + 4 <= r1; j += 4) {
        u32 e[4];
        u32 v[4];
#pragma unroll
        for (int q = 0; q < 4; ++q) e[q] = csr[j + q];
#pragma unroll
        for (int q = 0; q < 4; ++q) v[q] = *(const u32*)&In[(size_t)(e[q] & 0xffff) * 128 + c];
#pragma unroll
        for (int q = 0; q < 4; ++q) {
            float w = edge_w(e[q]);
            a0 = fmaf(w, bf2f((u16)(v[q] & 0xffff)), a0);
            a1 = fmaf(w, bf2f((u16)(v[q] >> 16)), a1);
        }
    }
    for (; j < r1; ++j) {
        u32 e = csr[j];
        u32 v = *(const u32*)&In[(size_t)(e & 0xffff) * 128 + c];
        float w = edge_w(e);
        a0 = fmaf(w, bf2f((u16)(v & 0xffff)), a0);
        a1 = fmaf(w, bf2f((u16)(v >> 16)), a1);
    }
    u32 o = ((u32)f2bf(di * a1) << 16) | (u32)f2bf(di * a0);
    *(u32*)&Out[(size_t)node * 128 + c] = o;
}

// ---------------------------------------------------------------------------
// GCN aggregation layer 2, fp8 e4m3 in -> bf16 out. One wave per node.
// ---------------------------------------------------------------------------
__global__ __launch_bounds__(256)
void agg256_fp8_kernel(const u8* __restrict__ In, const float* __restrict__ dinv,
                       const int* __restrict__ rp, const u32* __restrict__ csr,
                       u16* __restrict__ Out) {
    int node = blockIdx.x * 4 + (threadIdx.x >> 6);
    int lane = threadIdx.x & 63;
    if (node >= N_NODES) return;
    int c = lane * 4;
    float di = dinv[node];
    int r0 = rp[node], r1 = rp[node + 1];
    u32 sv = *(const u32*)&In[(size_t)node * 256 + c];
    f32x2 s01 = __builtin_amdgcn_cvt_pk_f32_fp8(sv, false);
    f32x2 s23 = __builtin_amdgcn_cvt_pk_f32_fp8(sv, true);
    float a0 = di * s01.x;
    float a1 = di * s01.y;
    float a2 = di * s23.x;
    float a3 = di * s23.y;
    int j = r0;
    for (; j + 8 <= r1; j += 8) {
        u32 e[8];
        u32 v[8];
#pragma unroll
        for (int q = 0; q < 8; ++q) e[q] = csr[j + q];
#pragma unroll
        for (int q = 0; q < 8; ++q) v[q] = *(const u32*)&In[(size_t)(e[q] & 0xffff) * 256 + c];
#pragma unroll
        for (int q = 0; q < 8; ++q) {
            float w = edge_w(e[q]);
            f32x2 p0 = __builtin_amdgcn_cvt_pk_f32_fp8(v[q], false);
            f32x2 p1 = __builtin_amdgcn_cvt_pk_f32_fp8(v[q], true);
            a0 = fmaf(w, p0.x, a0);
            a1 = fmaf(w, p0.y, a1);
            a2 = fmaf(w, p1.x, a2);
            a3 = fmaf(w, p1.y, a3);
        }
    }
    for (; j + 4 <= r1; j += 4) {
        u32 e[4];
        u32 v[4];
#pragma unroll
        for (int q = 0; q < 4; ++q) e[q] = csr[j + q];
#pragma unroll
        for (int q = 0; q < 4; ++q) v[q] = *(const u32*)&In[(size_t)(e[q] & 0xffff) * 256 + c];
#pragma unroll
        for (int q = 0; q < 4; ++q) {
            float w = edge_w(e[q]);
            f32x2 p0 = __builtin_amdgcn_cvt_pk_f32_fp8(v[q], false);
            f32x2 p1 = __builtin_amdgcn_cvt_pk_f32_fp8(v[q], true);
            a0 = fmaf(w, p0.x, a0);
            a1 = fmaf(w, p0.y, a1);
            a2 = fmaf(w, p1.x, a2);
            a3 = fmaf(w, p1.y, a3);
        }
    }
    for (; j < r1; ++j) {
        u32 e = csr[j];
        u32 v = *(const u32*)&In[(size_t)(e & 0xffff) * 256 + c];
        float w = edge_w(e);
        f32x2 p0 = __builtin_amdgcn_cvt_pk_f32_fp8(v, false);
        f32x2 p1 = __builtin_amdgcn_cvt_pk_f32_fp8(v, true);
        a0 = fmaf(w, p0.x, a0);
        a1 = fmaf(w, p0.y, a1);
        a2 = fmaf(w, p1.x, a2);
        a3 = fmaf(w, p1.y, a3);
    }
    uint2 o;
    o.x = ((u32)f2bf(di * a1) << 16) | (u32)f2bf(di * a0);
    o.y = ((u32)f2bf(di * a3) << 16) | (u32)f2bf(di * a2);
    *(uint2*)&Out[(size_t)node * 256 + c] = o;
}

// ---------------------------------------------------------------------------
// MFMA GEMM layer 1: H1[M,256] = relu( A[M,128] @ W1 + b1 ), fp8 e4m3 out
// ---------------------------------------------------------------------------
template<int K>
__global__ __launch_bounds__(256, 3)
void gemm1_kernel(const u16* __restrict__ A, const short8* __restrict__ Bswz,
                  const float* __restrict__ bias, u8* __restrict__ Out, int M) {
    const int KS = K / 32;
    __shared__ u16 cst[64][264];
    int tid  = threadIdx.x;
    int wave = tid >> 6, lane = tid & 63;
    int m0 = blockIdx.x * 64;
    int n0 = wave * 64;
    int lr = lane & 15;
    int lk = (lane >> 4) * 8;

    f32x4 acc[4][4];
#pragma unroll
    for (int i = 0; i < 4; ++i)
#pragma unroll
        for (int j = 0; j < 4; ++j) acc[i][j] = {0.f, 0.f, 0.f, 0.f};

    for (int k0i = 0; k0i < KS; ++k0i) {
        int k0 = k0i * 32;
        short8 a[4], bh[4], bl[4];
#pragma unroll
        for (int mt = 0; mt < 4; ++mt) {
            int m = m0 + mt * 16 + lr;
            if (m > M - 1) m = M - 1;
            a[mt] = *(const short8*)&A[(size_t)m * K + k0 + lk];
        }
        const short8* bp = Bswz + ((size_t)(wave * KS + k0i) * 8) * 64 + lane;
#pragma unroll
        for (int nt = 0; nt < 4; ++nt) {
            bh[nt] = bp[(size_t)nt * 64];
            bl[nt] = bp[(size_t)(4 + nt) * 64];
        }
#pragma unroll
        for (int mt = 0; mt < 4; ++mt)
#pragma unroll
            for (int nt = 0; nt < 4; ++nt) {
                acc[mt][nt] = __builtin_amdgcn_mfma_f32_16x16x32_bf16(a[mt], bh[nt], acc[mt][nt], 0, 0, 0);
                acc[mt][nt] = __builtin_amdgcn_mfma_f32_16x16x32_bf16(a[mt], bl[nt], acc[mt][nt], 0, 0, 0);
            }
    }

#pragma unroll
    for (int mt = 0; mt < 4; ++mt)
#pragma unroll
        for (int nt = 0; nt < 4; ++nt) {
            int col = n0 + nt * 16 + lr;
            float b = bias[col];
#pragma unroll
            for (int r = 0; r < 4; ++r) {
                int row = mt * 16 + (lane >> 4) * 4 + r;
                cst[row][col] = f2bf(fmaxf(acc[mt][nt][r] + b, 0.f));
            }
        }
    __syncthreads();
#pragma unroll
    for (int p = 0; p < 8; ++p) {
        int row = p * 8 + (tid >> 5);
        int c16 = (tid & 31) * 8;
        int m = m0 + row;
        if (m < M) {
            uint4 v = *(const uint4*)&cst[row][c16];
            uint2 o = make_uint2(pack4_fp8(v.x, v.y), pack4_fp8(v.z, v.w));
            *(uint2*)&Out[(size_t)m * 256 + c16] = o;
        }
    }
}

// ---------------------------------------------------------------------------
// MFMA GEMM layer 2 + fused mean-pool
// ---------------------------------------------------------------------------
__global__ __launch_bounds__(256, 3)
void gemm2_pool_kernel(const u16* __restrict__ A, const short8* __restrict__ Bswz,
                       const float* __restrict__ bias, const int* __restrict__ batch,
                       float* __restrict__ pooled, int M) {
    const int K = H_DIM, KS = K / 32;
    __shared__ u16 cst[64][264];
    __shared__ int batch_s[64];
    int tid  = threadIdx.x;
    int wave = tid >> 6, lane = tid & 63;
    int m0 = blockIdx.x * 64;
    int n0 = wave * 64;
    int lr = lane & 15;
    int lk = (lane >> 4) * 8;

    f32x4 acc[4][4];
#pragma unroll
    for (int i = 0; i < 4; ++i)
#pragma unroll
        for (int j = 0; j < 4; ++j) acc[i][j] = {0.f, 0.f, 0.f, 0.f};

    for (int k0i = 0; k0i < KS; ++k0i) {
        int k0 = k0i * 32;
        short8 a[4], bh[4], bl[4];
#pragma unroll
        for (int mt = 0; mt < 4; ++mt) {
            int m = m0 + mt * 16 + lr;
            if (m > M - 1) m = M - 1;
            a[mt] = *(const short8*)&A[(size_t)m * K + k0 + lk];
        }
        const short8* bp = Bswz + ((size_t)(wave * KS + k0i) * 8) * 64 + lane;
#pragma unroll
        for (int nt = 0; nt < 4; ++nt) {
            bh[nt] = bp[(size_t)nt * 64];
            bl[nt] = bp[(size_t)(4 + nt) * 64];
        }
#pragma unroll
        for (int mt = 0; mt < 4; ++mt)
#pragma unroll
            for (int nt = 0; nt < 4; ++nt) {
                acc[mt][nt] = __builtin_amdgcn_mfma_f32_16x16x32_bf16(a[mt], bh[nt], acc[mt][nt], 0, 0, 0);
                acc[mt][nt] = __builtin_amdgcn_mfma_f32_16x16x32_bf16(a[mt], bl[nt], acc[mt][nt], 0, 0, 0);
            }
    }

    if (tid < 64) {
        int m = m0 + tid;
        batch_s[tid] = (m < M) ? batch[m] : -1;
    }
#pragma unroll
    for (int mt = 0; mt < 4; ++mt)
#pragma unroll
        for (int nt = 0; nt < 4; ++nt) {
            int col = n0 + nt * 16 + lr;
            float b = bias[col];
#pragma unroll
            for (int r = 0; r < 4; ++r) {
                int row = mt * 16 + (lane >> 4) * 4 + r;
                cst[row][col] = f2bf(fmaxf(acc[mt][nt][r] + b, 0.f));
            }
        }
    __syncthreads();

    // segmented pooling: thread = column, walk the 64 sorted rows
    int rows = M - m0; if (rows > 64) rows = 64;
    float s = 0.f;
    int gp = batch_s[0];
    for (int r = 0; r < rows; ++r) {
        int g = batch_s[r];
        if (g != gp) {
            atomicAdd(&pooled[(size_t)gp * H_DIM + tid], s);
            s = 0.f;
            gp = g;
        }
        s += bf2f(cst[r][tid]);
    }
    atomicAdd(&pooled[(size_t)gp * H_DIM + tid], s);
}

// ---------------------------------------------------------------------------
// Heads (fp32): h_graph = pooled/cnt (cnt from goff diffs); mu/logvar heads
// ---------------------------------------------------------------------------
__global__ void head_kernel(const float* __restrict__ pooled, const int* __restrict__ goff,
                            const float* __restrict__ Wmu, const float* __restrict__ bmu,
                            const float* __restrict__ Wlv, const float* __restrict__ blv,
                            float* __restrict__ out) {
    __shared__ float hg[H_DIM];
    int g = blockIdx.x, l = threadIdx.x;   // 64 threads
    float inv = 1.0f / fmaxf((float)(goff[g + 1] - goff[g]), 1.0f);
    for (int k = l; k < H_DIM; k += 64) hg[k] = pooled[(size_t)g * H_DIM + k] * inv;
    __syncthreads();
    float mu = bmu[l], lv = blv[l];
    for (int k = 0; k < H_DIM; ++k) {
        float h = hg[k];
        mu = fmaf(h, Wmu[k * L_DIM + l], mu);
        lv = fmaf(h, Wlv[k * L_DIM + l], lv);
    }
    out[(size_t)g * L_DIM + l] = mu;
    out[(size_t)G_NUM * L_DIM + (size_t)g * L_DIM + l] = lv;
}

// ---------------------------------------------------------------------------
extern "C" void kernel_launch(void* const* d_in, const int* in_sizes, int n_in,
                              void* d_out, int out_size, void* d_ws, size_t ws_size,
                              hipStream_t stream) {
    const float* x     = (const float*)d_in[0];
    const int*   ei    = (const int*)  d_in[1];
    const int*   batch = (const int*)  d_in[2];
    const float* W1  = (const float*)d_in[4];
    const float* b1  = (const float*)d_in[5];
    const float* W2  = (const float*)d_in[6];
    const float* b2  = (const float*)d_in[7];
    const float* Wmu = (const float*)d_in[8];
    const float* bmu = (const float*)d_in[9];
    const float* Wlv = (const float*)d_in[10];
    const float* blv = (const float*)d_in[11];
    const int* src = ei;
    const int* dst = ei + N_EDGES;

    char* ws = (char*)d_ws;
    size_t off = 0;
    auto alloc = [&](size_t bytes) -> void* {
        void* p = ws + off;
        off += (bytes + 255) & ~(size_t)255;
        return p;
    };
    // hist + pooled adjacent -> one memset clears both
    int*   hist     = (int*)alloc((size_t)N_NODES * 4);
    float* pooled   = (float*)alloc((size_t)G_NUM * H_DIM * 4);
    float* dinv     = (float*)alloc((size_t)N_NODES * 4);
    int*   row_ptr  = (int*)alloc((size_t)(N_NODES + 1) * 4);
    int*   cursor   = (int*)alloc((size_t)N_NODES * 4);
    u32*   csr      = (u32*)alloc((size_t)N_EDGES * 4);
    int*   excl     = (int*)alloc((size_t)N_NODES * 4);
    int*   partials = (int*)alloc(256 * 4);
    int*   goff     = (int*)alloc((size_t)(G_NUM + 1) * 4);
    u16*   xb    = (u16*)alloc((size_t)N_NODES * F_IN_D * 2);  // 12.8 MB
    u16*   Xa    = (u16*)alloc((size_t)N_NODES * F_IN_D * 2);  // 12.8 MB
    u8*    H8    = (u8*)alloc((size_t)N_NODES * H_DIM);        // 12.8 MB (fp8)
    u16*   Ha    = (u16*)alloc((size_t)N_NODES * H_DIM * 2);   // 25.6 MB
    u16*   w1swz = (u16*)alloc((size_t)2 * F_IN_D * H_DIM * 2);
    u16*   w2swz = (u16*)alloc((size_t)2 * H_DIM * H_DIM * 2);
    (void)ws_size; (void)n_in; (void)in_sizes; (void)out_size;

    const int GEMM_NB = (N_NODES + 63) / 64;     // 782
    size_t zero_bytes = (size_t)((char*)(pooled + G_NUM * H_DIM) - (char*)hist);

    hipMemsetAsync(hist, 0, zero_bytes, stream);
    prep_kernel<<<NB_COUNT + NB_SCAN + NB_CONV, 256, 0, stream>>>(
        dst, hist, batch, goff, x, xb, W1, w1swz, W2, w2swz);
    scan_chunk_kernel<<<NB_SCAN, 256, 0, stream>>>(hist, excl, partials, dinv, N_NODES);
    scan_final_kernel<<<NB_SCAN, 256, 0, stream>>>(excl, partials, row_ptr, cursor, N_NODES, NB_SCAN);
    place_kernel<<<NB_PLACE, 256, 0, stream>>>(src, dst, dinv, cursor, csr);

    // layer 1: aggregate(x) then GEMM  (A_hat (X W) == (A_hat X) W)
    agg128_kernel<<<(N_NODES + 3) / 4, 256, 0, stream>>>(xb, dinv, row_ptr, csr, Xa);
    gemm1_kernel<F_IN_D><<<GEMM_NB, 256, 0, stream>>>(Xa, (const short8*)w1swz, b1, H8, N_NODES);
    // layer 2: aggregate(H1 fp8) then GEMM with fused mean-pool
    agg256_fp8_kernel<<<(N_NODES + 3) / 4, 256, 0, stream>>>(H8, dinv, row_ptr, csr, Ha);
    gemm2_pool_kernel<<<GEMM_NB, 256, 0, stream>>>(Ha, (const short8*)w2swz, b2, batch, pooled, N_NODES);

    head_kernel<<<G_NUM, 64, 0, stream>>>(pooled, goff, Wmu, bmu, Wlv, blv, (float*)d_out);
}

// Round 3
// 309.818 us; speedup vs baseline: 1.0382x; 1.0382x over previous
//
#include <hip/hip_runtime.h>
#include <hip/hip_fp16.h>

// Problem constants (from the reference file)
#define N_NODES 50000
#define N_EDGES 800000
#define F_IN_D  128
#define H_DIM   256
#define L_DIM   64
#define G_NUM   500

typedef unsigned int   u32;
typedef unsigned short u16;
typedef unsigned char  u8;
typedef __attribute__((ext_vector_type(8))) short short8;
typedef __attribute__((ext_vector_type(4))) float f32x4;
typedef __attribute__((ext_vector_type(2))) float f32x2;

// cursor padded: one counter per 64B line to kill same-line atomic serialization
#define CUR_STRIDE 16

static __device__ __forceinline__ float bf2f(u16 u) {
    union { u32 i; float f; } x; x.i = ((u32)u) << 16; return x.f;
}
static __device__ __forceinline__ u16 f2bf(float f) {
    union { float f; u32 i; } x; x.f = f;
    u32 r = (x.i + 0x7fffu + ((x.i >> 16) & 1u)) >> 16;
    return (u16)r;
}
// csr entry: src node in low 16 bits (N_NODES < 65536), fp16(dinv[src]) in high 16
static __device__ __forceinline__ float edge_w(u32 e) {
    return __half2float(__ushort_as_half((u16)(e >> 16)));
}

// pack two bf16-pairs (4 values) into 4 fp8 e4m3 bytes via HW converter
static __device__ __forceinline__ u32 pack4_fp8(u32 a, u32 b) {
    u32 w = __builtin_amdgcn_cvt_pk_fp8_f32(bf2f((u16)(a & 0xffff)),
                                            bf2f((u16)(a >> 16)), 0, false);
    w = __builtin_amdgcn_cvt_pk_fp8_f32(bf2f((u16)(b & 0xffff)),
                                        bf2f((u16)(b >> 16)), w, true);
    return w;
}

// B-swizzle address (in u16 units): fragment layout for mfma_16x16x32_bf16.
static __device__ __forceinline__ u32 bswz_idx(int n, int k, int plane, int KS) {
    int n0g = n >> 6, nt = (n >> 4) & 3, lr = n & 15;
    int k0i = k >> 5, ks = k & 31, lq = ks >> 3, j = ks & 7;
    return ((u32)((((n0g * KS + k0i) * 2 + plane) * 4 + nt) * 64 + lq * 16 + lr)) * 8 + j;
}

// ---------------------------------------------------------------------------
// Fused preprocessing: degree count + batch bounds + all dtype conversions.
// ---------------------------------------------------------------------------
#define NXQ (N_NODES * F_IN_D / 4)          // 1,600,000
#define NW1 (F_IN_D * H_DIM)                // 32,768
#define NW2 (H_DIM * H_DIM)                 // 65,536
#define NB_COUNT ((N_EDGES + 255) / 256)            // 3125
#define NB_SCAN  ((N_NODES + 255) / 256)            // 196
#define NB_CONV  ((NXQ + NW1 + NW2 + 255) / 256)    // 6634

__global__ void prep_kernel(const int* __restrict__ dst, int* __restrict__ hist,
                            const int* __restrict__ batch, int* __restrict__ goff,
                            const float* __restrict__ x, u16* __restrict__ xb,
                            const float* __restrict__ W1, u16* __restrict__ w1swz,
                            const float* __restrict__ W2, u16* __restrict__ w2swz) {
    int b = blockIdx.x;
    if (b < NB_COUNT) {
        int i = b * 256 + threadIdx.x;
        if (i < N_EDGES) atomicAdd(&hist[dst[i]], 1);
    } else if (b < NB_COUNT + NB_SCAN) {
        int i = (b - NB_COUNT) * 256 + threadIdx.x;
        if (i >= N_NODES) return;
        int v = batch[i];
        if (i == 0) {
            for (int g = 0; g <= v; ++g) goff[g] = 0;
        } else {
            int p = batch[i - 1];
            for (int g = p + 1; g <= v; ++g) goff[g] = i;
        }
        if (i == N_NODES - 1) {
            for (int g = v + 1; g <= G_NUM; ++g) goff[g] = N_NODES;
        }
    } else {
        int i = (b - NB_COUNT - NB_SCAN) * 256 + threadIdx.x;
        if (i < NXQ) {
            float4 v = *(const float4*)&x[(size_t)i * 4];
            ushort4 o;
            o.x = f2bf(v.x); o.y = f2bf(v.y); o.z = f2bf(v.z); o.w = f2bf(v.w);
            *(ushort4*)&xb[(size_t)i * 4] = o;
        } else if (i < NXQ + NW1) {
            int idx = i - NXQ;
            int k = idx >> 8, n = idx & 255;
            float w = W1[idx];
            u16 h = f2bf(w);
            w1swz[bswz_idx(n, k, 0, F_IN_D / 32)] = h;
            w1swz[bswz_idx(n, k, 1, F_IN_D / 32)] = f2bf(w - bf2f(h));
        } else if (i < NXQ + NW1 + NW2) {
            int idx = i - NXQ - NW1;
            int k = idx >> 8, n = idx & 255;
            float w = W2[idx];
            u16 h = f2bf(w);
            w2swz[bswz_idx(n, k, 0, H_DIM / 32)] = h;
            w2swz[bswz_idx(n, k, 1, H_DIM / 32)] = f2bf(w - bf2f(h));
        }
    }
}

// exclusive scan of hist (chunk=256) + fused dinv computation
__global__ void scan_chunk_kernel(const int* __restrict__ in, int* __restrict__ excl,
                                  int* __restrict__ partials, float* __restrict__ dinv, int n) {
    __shared__ int sm[256];
    int t = threadIdx.x;
    int i = blockIdx.x * 256 + t;
    int v = (i < n) ? in[i] : 0;
    sm[t] = v; __syncthreads();
    for (int off = 1; off < 256; off <<= 1) {
        int x = (t >= off) ? sm[t - off] : 0;
        __syncthreads();
        sm[t] += x;
        __syncthreads();
    }
    if (i < n) {
        excl[i] = sm[t] - v;
        dinv[i] = 1.0f / sqrtf((float)(v + 1));   // +1 self loop
    }
    if (t == 255) partials[blockIdx.x] = sm[255];
}

__global__ void scan_final_kernel(const int* __restrict__ excl, const int* __restrict__ partials,
                                  int* __restrict__ out, int* __restrict__ cursor, int n, int nb) {
    __shared__ int sm[256];
    int t = threadIdx.x;
    int v = (t < nb) ? partials[t] : 0;
    sm[t] = v; __syncthreads();
    for (int off = 1; off < 256; off <<= 1) {
        int x = (t >= off) ? sm[t - off] : 0;
        __syncthreads();
        sm[t] += x;
        __syncthreads();
    }
    int pre = (blockIdx.x > 0) ? sm[blockIdx.x - 1] : 0;   // uniform read
    int i = blockIdx.x * 256 + t;
    if (i < n) {
        int val = excl[i] + pre;
        out[i] = val;
        cursor[(size_t)i * CUR_STRIDE] = val;   // padded: 1 counter / 64B line
    }
    if (blockIdx.x == (unsigned)(nb - 1) && t == 0) out[n] = sm[nb - 1];
}

// ---------------------------------------------------------------------------
// CSR placement. One edge per thread (max occupancy to hide the atomic
// round-trip); cursor padded to 1 counter/line so same-line RMW serialization
// at the coherent point drops from ~256 to ~16 per line.
// ---------------------------------------------------------------------------
__global__ __launch_bounds__(256)
void place_kernel(const int* __restrict__ src, const int* __restrict__ dst,
                  const float* __restrict__ dinv,
                  int* __restrict__ cursor, u32* __restrict__ csr) {
    int e = blockIdx.x * 256 + threadIdx.x;
    if (e < N_EDGES) {
        int s = src[e];
        int d = dst[e];
        float di = dinv[s];
        int pos = atomicAdd(&cursor[(size_t)d * CUR_STRIDE], 1);
        u32 h = (u32)__half_as_ushort(__float2half(di));
        csr[pos] = (u32)s | (h << 16);
    }
}

// ---------------------------------------------------------------------------
// GCN aggregation layer 1, bf16 in -> bf16 out. One wave per node.
// ---------------------------------------------------------------------------
__global__ __launch_bounds__(256)
void agg128_kernel(const u16* __restrict__ In, const float* __restrict__ dinv,
                   const int* __restrict__ rp, const u32* __restrict__ csr,
                   u16* __restrict__ Out) {
    int node = blockIdx.x * 4 + (threadIdx.x >> 6);
    int lane = threadIdx.x & 63;
    if (node >= N_NODES) return;
    int c = lane * 2;
    float di = dinv[node];
    int r0 = rp[node], r1 = rp[node + 1];
    u32 sv = *(const u32*)&In[(size_t)node * 128 + c];
    float a0 = di * bf2f((u16)(sv & 0xffff));
    float a1 = di * bf2f((u16)(sv >> 16));
    int j = r0;
    for (; j + 8 <= r1; j += 8) {
        u32 e[8];
        u32 v[8];
#pragma unroll
        for (int q = 0; q < 8; ++q) e[q] = csr[j + q];
#pragma unroll
        for (int q = 0; q < 8; ++q) v[q] = *(const u32*)&In[(size_t)(e[q] & 0xffff) * 128 + c];
#pragma unroll
        for (int q = 0; q < 8; ++q) {
            float w = edge_w(e[q]);
            a0 = fmaf(w, bf2f((u16)(v[q] & 0xffff)), a0);
            a1 = fmaf(w, bf2f((u16)(v[q] >> 16)), a1);
        }
    }
    for (; j + 4 <= r1; j += 4) {
        u32 e[4];
        u32 v[4];
#pragma unroll
        for (int q = 0; q < 4; ++q) e[q] = csr[j + q];
#pragma unroll
        for (int q = 0; q < 4; ++q) v[q] = *(const u32*)&In[(size_t)(e[q] & 0xffff) * 128 + c];
#pragma unroll
        for (int q = 0; q < 4; ++q) {
            float w = edge_w(e[q]);
            a0 = fmaf(w, bf2f((u16)(v[q] & 0xffff)), a0);
            a1 = fmaf(w, bf2f((u16)(v[q] >> 16)), a1);
        }
    }
    for (; j < r1; ++j) {
        u32 e = csr[j];
        u32 v = *(const u32*)&In[(size_t)(e & 0xffff) * 128 + c];
        float w = edge_w(e);
        a0 = fmaf(w, bf2f((u16)(v & 0xffff)), a0);
        a1 = fmaf(w, bf2f((u16)(v >> 16)), a1);
    }
    u32 o = ((u32)f2bf(di * a1) << 16) | (u32)f2bf(di * a0);
    *(u32*)&Out[(size_t)node * 128 + c] = o;
}

// ---------------------------------------------------------------------------
// GCN aggregation layer 2, fp8 e4m3 in -> bf16 out. One wave per node.
// ---------------------------------------------------------------------------
__global__ __launch_bounds__(256)
void agg256_fp8_kernel(const u8* __restrict__ In, const float* __restrict__ dinv,
                       const int* __restrict__ rp, const u32* __restrict__ csr,
                       u16* __restrict__ Out) {
    int node = blockIdx.x * 4 + (threadIdx.x >> 6);
    int lane = threadIdx.x & 63;
    if (node >= N_NODES) return;
    int c = lane * 4;
    float di = dinv[node];
    int r0 = rp[node], r1 = rp[node + 1];
    u32 sv = *(const u32*)&In[(size_t)node * 256 + c];
    f32x2 s01 = __builtin_amdgcn_cvt_pk_f32_fp8(sv, false);
    f32x2 s23 = __builtin_amdgcn_cvt_pk_f32_fp8(sv, true);
    float a0 = di * s01.x;
    float a1 = di * s01.y;
    float a2 = di * s23.x;
    float a3 = di * s23.y;
    int j = r0;
    for (; j + 8 <= r1; j += 8) {
        u32 e[8];
        u32 v[8];
#pragma unroll
        for (int q = 0; q < 8; ++q) e[q] = csr[j + q];
#pragma unroll
        for (int q = 0; q < 8; ++q) v[q] = *(const u32*)&In[(size_t)(e[q] & 0xffff) * 256 + c];
#pragma unroll
        for (int q = 0; q < 8; ++q) {
            float w = edge_w(e[q]);
            f32x2 p0 = __builtin_amdgcn_cvt_pk_f32_fp8(v[q], false);
            f32x2 p1 = __builtin_amdgcn_cvt_pk_f32_fp8(v[q], true);
            a0 = fmaf(w, p0.x, a0);
            a1 = fmaf(w, p0.y, a1);
            a2 = fmaf(w, p1.x, a2);
            a3 = fmaf(w, p1.y, a3);
        }
    }
    for (; j + 4 <= r1; j += 4) {
        u32 e[4];
        u32 v[4];
#pragma unroll
        for (int q = 0; q < 4; ++q) e[q] = csr[j + q];
#pragma unroll
        for (int q = 0; q < 4; ++q) v[q] = *(const u32*)&In[(size_t)(e[q] & 0xffff) * 256 + c];
#pragma unroll
        for (int q = 0; q < 4; ++q) {
            float w = edge_w(e[q]);
            f32x2 p0 = __builtin_amdgcn_cvt_pk_f32_fp8(v[q], false);
            f32x2 p1 = __builtin_amdgcn_cvt_pk_f32_fp8(v[q], true);
            a0 = fmaf(w, p0.x, a0);
            a1 = fmaf(w, p0.y, a1);
            a2 = fmaf(w, p1.x, a2);
            a3 = fmaf(w, p1.y, a3);
        }
    }
    for (; j < r1; ++j) {
        u32 e = csr[j];
        u32 v = *(const u32*)&In[(size_t)(e & 0xffff) * 256 + c];
        float w = edge_w(e);
        f32x2 p0 = __builtin_amdgcn_cvt_pk_f32_fp8(v, false);
        f32x2 p1 = __builtin_amdgcn_cvt_pk_f32_fp8(v, true);
        a0 = fmaf(w, p0.x, a0);
        a1 = fmaf(w, p0.y, a1);
        a2 = fmaf(w, p1.x, a2);
        a3 = fmaf(w, p1.y, a3);
    }
    uint2 o;
    o.x = ((u32)f2bf(di * a1) << 16) | (u32)f2bf(di * a0);
    o.y = ((u32)f2bf(di * a3) << 16) | (u32)f2bf(di * a2);
    *(uint2*)&Out[(size_t)node * 256 + c] = o;
}

// ---------------------------------------------------------------------------
// MFMA GEMM layer 1: H1[M,256] = relu( A[M,128] @ W1 + b1 ), fp8 e4m3 out
// ---------------------------------------------------------------------------
template<int K>
__global__ __launch_bounds__(256, 3)
void gemm1_kernel(const u16* __restrict__ A, const short8* __restrict__ Bswz,
                  const float* __restrict__ bias, u8* __restrict__ Out, int M) {
    const int KS = K / 32;
    __shared__ u16 cst[64][264];
    int tid  = threadIdx.x;
    int wave = tid >> 6, lane = tid & 63;
    int m0 = blockIdx.x * 64;
    int n0 = wave * 64;
    int lr = lane & 15;
    int lk = (lane >> 4) * 8;

    f32x4 acc[4][4];
#pragma unroll
    for (int i = 0; i < 4; ++i)
#pragma unroll
        for (int j = 0; j < 4; ++j) acc[i][j] = {0.f, 0.f, 0.f, 0.f};

    for (int k0i = 0; k0i < KS; ++k0i) {
        int k0 = k0i * 32;
        short8 a[4], bh[4], bl[4];
#pragma unroll
        for (int mt = 0; mt < 4; ++mt) {
            int m = m0 + mt * 16 + lr;
            if (m > M - 1) m = M - 1;
            a[mt] = *(const short8*)&A[(size_t)m * K + k0 + lk];
        }
        const short8* bp = Bswz + ((size_t)(wave * KS + k0i) * 8) * 64 + lane;
#pragma unroll
        for (int nt = 0; nt < 4; ++nt) {
            bh[nt] = bp[(size_t)nt * 64];
            bl[nt] = bp[(size_t)(4 + nt) * 64];
        }
#pragma unroll
        for (int mt = 0; mt < 4; ++mt)
#pragma unroll
            for (int nt = 0; nt < 4; ++nt) {
                acc[mt][nt] = __builtin_amdgcn_mfma_f32_16x16x32_bf16(a[mt], bh[nt], acc[mt][nt], 0, 0, 0);
                acc[mt][nt] = __builtin_amdgcn_mfma_f32_16x16x32_bf16(a[mt], bl[nt], acc[mt][nt], 0, 0, 0);
            }
    }

#pragma unroll
    for (int mt = 0; mt < 4; ++mt)
#pragma unroll
        for (int nt = 0; nt < 4; ++nt) {
            int col = n0 + nt * 16 + lr;
            float b = bias[col];
#pragma unroll
            for (int r = 0; r < 4; ++r) {
                int row = mt * 16 + (lane >> 4) * 4 + r;
                cst[row][col] = f2bf(fmaxf(acc[mt][nt][r] + b, 0.f));
            }
        }
    __syncthreads();
#pragma unroll
    for (int p = 0; p < 8; ++p) {
        int row = p * 8 + (tid >> 5);
        int c16 = (tid & 31) * 8;
        int m = m0 + row;
        if (m < M) {
            uint4 v = *(const uint4*)&cst[row][c16];
            uint2 o = make_uint2(pack4_fp8(v.x, v.y), pack4_fp8(v.z, v.w));
            *(uint2*)&Out[(size_t)m * 256 + c16] = o;
        }
    }
}

// ---------------------------------------------------------------------------
// MFMA GEMM layer 2 + fused mean-pool
// ---------------------------------------------------------------------------
__global__ __launch_bounds__(256, 3)
void gemm2_pool_kernel(const u16* __restrict__ A, const short8* __restrict__ Bswz,
                       const float* __restrict__ bias, const int* __restrict__ batch,
                       float* __restrict__ pooled, int M) {
    const int K = H_DIM, KS = K / 32;
    __shared__ u16 cst[64][264];
    __shared__ int batch_s[64];
    int tid  = threadIdx.x;
    int wave = tid >> 6, lane = tid & 63;
    int m0 = blockIdx.x * 64;
    int n0 = wave * 64;
    int lr = lane & 15;
    int lk = (lane >> 4) * 8;

    f32x4 acc[4][4];
#pragma unroll
    for (int i = 0; i < 4; ++i)
#pragma unroll
        for (int j = 0; j < 4; ++j) acc[i][j] = {0.f, 0.f, 0.f, 0.f};

    for (int k0i = 0; k0i < KS; ++k0i) {
        int k0 = k0i * 32;
        short8 a[4], bh[4], bl[4];
#pragma unroll
        for (int mt = 0; mt < 4; ++mt) {
            int m = m0 + mt * 16 + lr;
            if (m > M - 1) m = M - 1;
            a[mt] = *(const short8*)&A[(size_t)m * K + k0 + lk];
        }
        const short8* bp = Bswz + ((size_t)(wave * KS + k0i) * 8) * 64 + lane;
#pragma unroll
        for (int nt = 0; nt < 4; ++nt) {
            bh[nt] = bp[(size_t)nt * 64];
            bl[nt] = bp[(size_t)(4 + nt) * 64];
        }
#pragma unroll
        for (int mt = 0; mt < 4; ++mt)
#pragma unroll
            for (int nt = 0; nt < 4; ++nt) {
                acc[mt][nt] = __builtin_amdgcn_mfma_f32_16x16x32_bf16(a[mt], bh[nt], acc[mt][nt], 0, 0, 0);
                acc[mt][nt] = __builtin_amdgcn_mfma_f32_16x16x32_bf16(a[mt], bl[nt], acc[mt][nt], 0, 0, 0);
            }
    }

    if (tid < 64) {
        int m = m0 + tid;
        batch_s[tid] = (m < M) ? batch[m] : -1;
    }
#pragma unroll
    for (int mt = 0; mt < 4; ++mt)
#pragma unroll
        for (int nt = 0; nt < 4; ++nt) {
            int col = n0 + nt * 16 + lr;
            float b = bias[col];
#pragma unroll
            for (int r = 0; r < 4; ++r) {
                int row = mt * 16 + (lane >> 4) * 4 + r;
                cst[row][col] = f2bf(fmaxf(acc[mt][nt][r] + b, 0.f));
            }
        }
    __syncthreads();

    // segmented pooling: thread = column, walk the 64 sorted rows
    int rows = M - m0; if (rows > 64) rows = 64;
    float s = 0.f;
    int gp = batch_s[0];
    for (int r = 0; r < rows; ++r) {
        int g = batch_s[r];
        if (g != gp) {
            atomicAdd(&pooled[(size_t)gp * H_DIM + tid], s);
            s = 0.f;
            gp = g;
        }
        s += bf2f(cst[r][tid]);
    }
    atomicAdd(&pooled[(size_t)gp * H_DIM + tid], s);
}

// ---------------------------------------------------------------------------
// Heads (fp32): h_graph = pooled/cnt (cnt from goff diffs); mu/logvar heads
// ---------------------------------------------------------------------------
__global__ void head_kernel(const float* __restrict__ pooled, const int* __restrict__ goff,
                            const float* __restrict__ Wmu, const float* __restrict__ bmu,
                            const float* __restrict__ Wlv, const float* __restrict__ blv,
                            float* __restrict__ out) {
    __shared__ float hg[H_DIM];
    int g = blockIdx.x, l = threadIdx.x;   // 64 threads
    float inv = 1.0f / fmaxf((float)(goff[g + 1] - goff[g]), 1.0f);
    for (int k = l; k < H_DIM; k += 64) hg[k] = pooled[(size_t)g * H_DIM + k] * inv;
    __syncthreads();
    float mu = bmu[l], lv = blv[l];
    for (int k = 0; k < H_DIM; ++k) {
        float h = hg[k];
        mu = fmaf(h, Wmu[k * L_DIM + l], mu);
        lv = fmaf(h, Wlv[k * L_DIM + l], lv);
    }
    out[(size_t)g * L_DIM + l] = mu;
    out[(size_t)G_NUM * L_DIM + (size_t)g * L_DIM + l] = lv;
}

// ---------------------------------------------------------------------------
extern "C" void kernel_launch(void* const* d_in, const int* in_sizes, int n_in,
                              void* d_out, int out_size, void* d_ws, size_t ws_size,
                              hipStream_t stream) {
    const float* x     = (const float*)d_in[0];
    const int*   ei    = (const int*)  d_in[1];
    const int*   batch = (const int*)  d_in[2];
    const float* W1  = (const float*)d_in[4];
    const float* b1  = (const float*)d_in[5];
    const float* W2  = (const float*)d_in[6];
    const float* b2  = (const float*)d_in[7];
    const float* Wmu = (const float*)d_in[8];
    const float* bmu = (const float*)d_in[9];
    const float* Wlv = (const float*)d_in[10];
    const float* blv = (const float*)d_in[11];
    const int* src = ei;
    const int* dst = ei + N_EDGES;

    char* ws = (char*)d_ws;
    size_t off = 0;
    auto alloc = [&](size_t bytes) -> void* {
        void* p = ws + off;
        off += (bytes + 255) & ~(size_t)255;
        return p;
    };
    // hist + pooled adjacent -> one memset clears both
    int*   hist     = (int*)alloc((size_t)N_NODES * 4);
    float* pooled   = (float*)alloc((size_t)G_NUM * H_DIM * 4);
    float* dinv     = (float*)alloc((size_t)N_NODES * 4);
    int*   row_ptr  = (int*)alloc((size_t)(N_NODES + 1) * 4);
    int*   cursor   = (int*)alloc((size_t)N_NODES * 4 * CUR_STRIDE);  // 3.2 MB padded
    u32*   csr      = (u32*)alloc((size_t)N_EDGES * 4);
    int*   excl     = (int*)alloc((size_t)N_NODES * 4);
    int*   partials = (int*)alloc(256 * 4);
    int*   goff     = (int*)alloc((size_t)(G_NUM + 1) * 4);
    u16*   xb    = (u16*)alloc((size_t)N_NODES * F_IN_D * 2);  // 12.8 MB
    u16*   Xa    = (u16*)alloc((size_t)N_NODES * F_IN_D * 2);  // 12.8 MB
    u8*    H8    = (u8*)alloc((size_t)N_NODES * H_DIM);        // 12.8 MB (fp8)
    u16*   Ha    = (u16*)alloc((size_t)N_NODES * H_DIM * 2);   // 25.6 MB
    u16*   w1swz = (u16*)alloc((size_t)2 * F_IN_D * H_DIM * 2);
    u16*   w2swz = (u16*)alloc((size_t)2 * H_DIM * H_DIM * 2);
    (void)ws_size; (void)n_in; (void)in_sizes; (void)out_size;

    const int GEMM_NB = (N_NODES + 63) / 64;     // 782
    size_t zero_bytes = (size_t)((char*)(pooled + G_NUM * H_DIM) - (char*)hist);

    hipMemsetAsync(hist, 0, zero_bytes, stream);
    prep_kernel<<<NB_COUNT + NB_SCAN + NB_CONV, 256, 0, stream>>>(
        dst, hist, batch, goff, x, xb, W1, w1swz, W2, w2swz);
    scan_chunk_kernel<<<NB_SCAN, 256, 0, stream>>>(hist, excl, partials, dinv, N_NODES);
    scan_final_kernel<<<NB_SCAN, 256, 0, stream>>>(excl, partials, row_ptr, cursor, N_NODES, NB_SCAN);
    place_kernel<<<(N_EDGES + 255) / 256, 256, 0, stream>>>(src, dst, dinv, cursor, csr);

    // layer 1: aggregate(x) then GEMM  (A_hat (X W) == (A_hat X) W)
    agg128_kernel<<<(N_NODES + 3) / 4, 256, 0, stream>>>(xb, dinv, row_ptr, csr, Xa);
    gemm1_kernel<F_IN_D><<<GEMM_NB, 256, 0, stream>>>(Xa, (const short8*)w1swz, b1, H8, N_NODES);
    // layer 2: aggregate(H1 fp8) then GEMM with fused mean-pool
    agg256_fp8_kernel<<<(N_NODES + 3) / 4, 256, 0, stream>>>(H8, dinv, row_ptr, csr, Ha);
    gemm2_pool_kernel<<<GEMM_NB, 256, 0, stream>>>(Ha, (const short8*)w2swz, b2, batch, pooled, N_NODES);

    head_kernel<<<G_NUM, 64, 0, stream>>>(pooled, goff, Wmu, bmu, Wlv, blv, (float*)d_out);
}

// Round 5
// 298.358 us; speedup vs baseline: 1.0780x; 1.0384x over previous
//
#include <hip/hip_runtime.h>
#include <hip/hip_fp16.h>

// Problem constants (from the reference file)
#define N_NODES 50000
#define N_EDGES 800000
#define F_IN_D  128
#define H_DIM   256
#define L_DIM   64
#define G_NUM   500

typedef unsigned int   u32;
typedef unsigned short u16;
typedef unsigned char  u8;
typedef __attribute__((ext_vector_type(8))) short short8;
typedef __attribute__((ext_vector_type(4))) float f32x4;
typedef __attribute__((ext_vector_type(2))) float f32x2;

// bucket = dst >> 8 (256 nodes per bucket)
#define BSHIFT 8
#define NBUCK ((N_NODES + 255) >> BSHIFT)          // 196
#define CUR_STRIDE 16                               // 1 counter / 64B line
#define BIN_NB 512
#define EPB ((N_EDGES + BIN_NB - 1) / BIN_NB)       // 1563 edges per bin block

static __device__ __forceinline__ float bf2f(u16 u) {
    union { u32 i; float f; } x; x.i = ((u32)u) << 16; return x.f;
}
static __device__ __forceinline__ u16 f2bf(float f) {
    union { float f; u32 i; } x; x.f = f;
    u32 r = (x.i + 0x7fffu + ((x.i >> 16) & 1u)) >> 16;
    return (u16)r;
}
// csr entry: src node in low 16 bits (N_NODES < 65536), fp16(dinv[src]) in high 16
static __device__ __forceinline__ float edge_w(u32 e) {
    return __half2float(__ushort_as_half((u16)(e >> 16)));
}

// pack two bf16-pairs (4 values) into 4 fp8 e4m3 bytes via HW converter
static __device__ __forceinline__ u32 pack4_fp8(u32 a, u32 b) {
    u32 w = __builtin_amdgcn_cvt_pk_fp8_f32(bf2f((u16)(a & 0xffff)),
                                            bf2f((u16)(a >> 16)), 0, false);
    w = __builtin_amdgcn_cvt_pk_fp8_f32(bf2f((u16)(b & 0xffff)),
                                        bf2f((u16)(b >> 16)), w, true);
    return w;
}

// B-swizzle address (in u16 units): fragment layout for mfma_16x16x32_bf16.
static __device__ __forceinline__ u32 bswz_idx(int n, int k, int plane, int KS) {
    int n0g = n >> 6, nt = (n >> 4) & 3, lr = n & 15;
    int k0i = k >> 5, ks = k & 31, lq = ks >> 3, j = ks & 7;
    return ((u32)((((n0g * KS + k0i) * 2 + plane) * 4 + nt) * 64 + lq * 16 + lr)) * 8 + j;
}

// ---------------------------------------------------------------------------
// Fused preprocessing: degree count + batch bounds + all dtype conversions.
// ---------------------------------------------------------------------------
#define NXQ (N_NODES * F_IN_D / 4)          // 1,600,000
#define NW1 (F_IN_D * H_DIM)                // 32,768
#define NW2 (H_DIM * H_DIM)                 // 65,536
#define NB_COUNT ((N_EDGES + 255) / 256)            // 3125
#define NB_SCAN  ((N_NODES + 255) / 256)            // 196
#define NB_CONV  ((NXQ + NW1 + NW2 + 255) / 256)    // 6634

__global__ void prep_kernel(const int* __restrict__ dst, int* __restrict__ hist,
                            const int* __restrict__ batch, int* __restrict__ goff,
                            const float* __restrict__ x, u16* __restrict__ xb,
                            const float* __restrict__ W1, u16* __restrict__ w1swz,
                            const float* __restrict__ W2, u16* __restrict__ w2swz) {
    int b = blockIdx.x;
    if (b < NB_COUNT) {
        int i = b * 256 + threadIdx.x;
        if (i < N_EDGES) atomicAdd(&hist[dst[i]], 1);
    } else if (b < NB_COUNT + NB_SCAN) {
        int i = (b - NB_COUNT) * 256 + threadIdx.x;
        if (i >= N_NODES) return;
        int v = batch[i];
        if (i == 0) {
            for (int g = 0; g <= v; ++g) goff[g] = 0;
        } else {
            int p = batch[i - 1];
            for (int g = p + 1; g <= v; ++g) goff[g] = i;
        }
        if (i == N_NODES - 1) {
            for (int g = v + 1; g <= G_NUM; ++g) goff[g] = N_NODES;
        }
    } else {
        int i = (b - NB_COUNT - NB_SCAN) * 256 + threadIdx.x;
        if (i < NXQ) {
            float4 v = *(const float4*)&x[(size_t)i * 4];
            ushort4 o;
            o.x = f2bf(v.x); o.y = f2bf(v.y); o.z = f2bf(v.z); o.w = f2bf(v.w);
            *(ushort4*)&xb[(size_t)i * 4] = o;
        } else if (i < NXQ + NW1) {
            int idx = i - NXQ;
            int k = idx >> 8, n = idx & 255;
            float w = W1[idx];
            u16 h = f2bf(w);
            w1swz[bswz_idx(n, k, 0, F_IN_D / 32)] = h;
            w1swz[bswz_idx(n, k, 1, F_IN_D / 32)] = f2bf(w - bf2f(h));
        } else if (i < NXQ + NW1 + NW2) {
            int idx = i - NXQ - NW1;
            int k = idx >> 8, n = idx & 255;
            float w = W2[idx];
            u16 h = f2bf(w);
            w2swz[bswz_idx(n, k, 0, H_DIM / 32)] = h;
            w2swz[bswz_idx(n, k, 1, H_DIM / 32)] = f2bf(w - bf2f(h));
        }
    }
}

// exclusive scan of hist (chunk=256) + fused dinv computation
__global__ void scan_chunk_kernel(const int* __restrict__ in, int* __restrict__ excl,
                                  int* __restrict__ partials, float* __restrict__ dinv, int n) {
    __shared__ int sm[256];
    int t = threadIdx.x;
    int i = blockIdx.x * 256 + t;
    int v = (i < n) ? in[i] : 0;
    sm[t] = v; __syncthreads();
    for (int off = 1; off < 256; off <<= 1) {
        int x = (t >= off) ? sm[t - off] : 0;
        __syncthreads();
        sm[t] += x;
        __syncthreads();
    }
    if (i < n) {
        excl[i] = sm[t] - v;
        dinv[i] = 1.0f / sqrtf((float)(v + 1));   // +1 self loop
    }
    if (t == 255) partials[blockIdx.x] = sm[255];
}

// final scan; also initializes the per-bucket bin cursors (bcur[b] = rp[b*256])
__global__ void scan_final_kernel(const int* __restrict__ excl, const int* __restrict__ partials,
                                  int* __restrict__ out, int* __restrict__ bcur, int n, int nb) {
    __shared__ int sm[256];
    int t = threadIdx.x;
    int v = (t < nb) ? partials[t] : 0;
    sm[t] = v; __syncthreads();
    for (int off = 1; off < 256; off <<= 1) {
        int x = (t >= off) ? sm[t - off] : 0;
        __syncthreads();
        sm[t] += x;
        __syncthreads();
    }
    int pre = (blockIdx.x > 0) ? sm[blockIdx.x - 1] : 0;   // uniform read
    int i = blockIdx.x * 256 + t;
    if (i < n) {
        int val = excl[i] + pre;
        out[i] = val;
        if ((i & 255) == 0) bcur[(i >> BSHIFT) * CUR_STRIDE] = val;
    }
    if (blockIdx.x == (unsigned)(nb - 1) && t == 0) out[n] = sm[nb - 1];
}

// ---------------------------------------------------------------------------
// CSR build, pass 1 (bin): two-pass per-block counting sort into 196 coarse
// buckets (dst>>8). One global atomicAdd per (block,bucket) reserves a
// contiguous run -> binrec writes are ~64B runs with a single writer per
// line (kills the 16x partial-line writeback amplification place_kernel had).
// ---------------------------------------------------------------------------
__global__ __launch_bounds__(256)
void bin_kernel(const int* __restrict__ src, const int* __restrict__ dst,
                const float* __restrict__ dinv,
                int* __restrict__ bcur, uint2* __restrict__ binrec) {
    __shared__ int lhist[NBUCK];
    __shared__ int lbase[NBUCK];
    int t = threadIdx.x;
    int e0 = blockIdx.x * EPB;
    int e1 = e0 + EPB; if (e1 > N_EDGES) e1 = N_EDGES;
    for (int i = t; i < NBUCK; i += 256) lhist[i] = 0;
    __syncthreads();
    for (int e = e0 + t; e < e1; e += 256)
        atomicAdd(&lhist[dst[e] >> BSHIFT], 1);
    __syncthreads();
    for (int i = t; i < NBUCK; i += 256) {
        int c = lhist[i];
        lbase[i] = c ? atomicAdd(&bcur[i * CUR_STRIDE], c) : 0;
        lhist[i] = 0;   // reuse as running rank cursor
    }
    __syncthreads();
    for (int e = e0 + t; e < e1; e += 256) {
        int d = dst[e], s = src[e];
        int bkt = d >> BSHIFT;
        int rank = atomicAdd(&lhist[bkt], 1);
        u32 w = (u32)__half_as_ushort(__float2half(dinv[s]));
        binrec[(size_t)lbase[bkt] + rank] = make_uint2((u32)s | (w << 16), (u32)(d & 255));
    }
}

// ---------------------------------------------------------------------------
// CSR build, pass 2 (group): one block per bucket streams the bucket's
// record slab and scatters within its 16KB csr window via LDS node cursors.
// Single-XCD, temporally-local stores -> L2 merges to full-line writebacks.
// ---------------------------------------------------------------------------
__global__ __launch_bounds__(256)
void grp_kernel(const int* __restrict__ rp, const uint2* __restrict__ binrec,
                u32* __restrict__ csr) {
    __shared__ int ncur[256];
    int b = blockIdx.x;
    int t = threadIdx.x;
    int n0 = b << BSHIFT;
    int n1 = n0 + 256; if (n1 > N_NODES) n1 = N_NODES;
    if (n0 + t < n1) ncur[t] = rp[n0 + t];
    __syncthreads();
    int s0 = rp[n0], s1 = rp[n1];
    for (int p = s0 + t; p < s1; p += 256) {
        uint2 r = binrec[p];
        int pos = atomicAdd(&ncur[r.y], 1);
        csr[pos] = r.x;
    }
}

// ---------------------------------------------------------------------------
// GCN aggregation layer 1, bf16 in -> bf16 out. One wave per node.
// ---------------------------------------------------------------------------
__global__ __launch_bounds__(256)
void agg128_kernel(const u16* __restrict__ In, const float* __restrict__ dinv,
                   const int* __restrict__ rp, const u32* __restrict__ csr,
                   u16* __restrict__ Out) {
    int node = blockIdx.x * 4 + (threadIdx.x >> 6);
    int lane = threadIdx.x & 63;
    if (node >= N_NODES) return;
    int c = lane * 2;
    float di = dinv[node];
    int r0 = rp[node], r1 = rp[node + 1];
    u32 sv = *(const u32*)&In[(size_t)node * 128 + c];
    float a0 = di * bf2f((u16)(sv & 0xffff));
    float a1 = di * bf2f((u16)(sv >> 16));
    int j = r0;
    for (; j + 8 <= r1; j += 8) {
        u32 e[8];
        u32 v[8];
#pragma unroll
        for (int q = 0; q < 8; ++q) e[q] = csr[j + q];
#pragma unroll
        for (int q = 0; q < 8; ++q) v[q] = *(const u32*)&In[(size_t)(e[q] & 0xffff) * 128 + c];
#pragma unroll
        for (int q = 0; q < 8; ++q) {
            float w = edge_w(e[q]);
            a0 = fmaf(w, bf2f((u16)(v[q] & 0xffff)), a0);
            a1 = fmaf(w, bf2f((u16)(v[q] >> 16)), a1);
        }
    }
    for (; j + 4 <= r1; j += 4) {
        u32 e[4];
        u32 v[4];
#pragma unroll
        for (int q = 0; q < 4; ++q) e[q] = csr[j + q];
#pragma unroll
        for (int q = 0; q < 4; ++q) v[q] = *(const u32*)&In[(size_t)(e[q] & 0xffff) * 128 + c];
#pragma unroll
        for (int q = 0; q < 4; ++q) {
            float w = edge_w(e[q]);
            a0 = fmaf(w, bf2f((u16)(v[q] & 0xffff)), a0);
            a1 = fmaf(w, bf2f((u16)(v[q] >> 16)), a1);
        }
    }
    for (; j < r1; ++j) {
        u32 e = csr[j];
        u32 v = *(const u32*)&In[(size_t)(e & 0xffff) * 128 + c];
        float w = edge_w(e);
        a0 = fmaf(w, bf2f((u16)(v & 0xffff)), a0);
        a1 = fmaf(w, bf2f((u16)(v >> 16)), a1);
    }
    u32 o = ((u32)f2bf(di * a1) << 16) | (u32)f2bf(di * a0);
    *(u32*)&Out[(size_t)node * 128 + c] = o;
}

// ---------------------------------------------------------------------------
// GCN aggregation layer 2, fp8 e4m3 in -> bf16 out. One wave per node.
// ---------------------------------------------------------------------------
__global__ __launch_bounds__(256)
void agg256_fp8_kernel(const u8* __restrict__ In, const float* __restrict__ dinv,
                       const int* __restrict__ rp, const u32* __restrict__ csr,
                       u16* __restrict__ Out) {
    int node = blockIdx.x * 4 + (threadIdx.x >> 6);
    int lane = threadIdx.x & 63;
    if (node >= N_NODES) return;
    int c = lane * 4;
    float di = dinv[node];
    int r0 = rp[node], r1 = rp[node + 1];
    u32 sv = *(const u32*)&In[(size_t)node * 256 + c];
    f32x2 s01 = __builtin_amdgcn_cvt_pk_f32_fp8(sv, false);
    f32x2 s23 = __builtin_amdgcn_cvt_pk_f32_fp8(sv, true);
    float a0 = di * s01.x;
    float a1 = di * s01.y;
    float a2 = di * s23.x;
    float a3 = di * s23.y;
    int j = r0;
    for (; j + 8 <= r1; j += 8) {
        u32 e[8];
        u32 v[8];
#pragma unroll
        for (int q = 0; q < 8; ++q) e[q] = csr[j + q];
#pragma unroll
        for (int q = 0; q < 8; ++q) v[q] = *(const u32*)&In[(size_t)(e[q] & 0xffff) * 256 + c];
#pragma unroll
        for (int q = 0; q < 8; ++q) {
            float w = edge_w(e[q]);
            f32x2 p0 = __builtin_amdgcn_cvt_pk_f32_fp8(v[q], false);
            f32x2 p1 = __builtin_amdgcn_cvt_pk_f32_fp8(v[q], true);
            a0 = fmaf(w, p0.x, a0);
            a1 = fmaf(w, p0.y, a1);
            a2 = fmaf(w, p1.x, a2);
            a3 = fmaf(w, p1.y, a3);
        }
    }
    for (; j + 4 <= r1; j += 4) {
        u32 e[4];
        u32 v[4];
#pragma unroll
        for (int q = 0; q < 4; ++q) e[q] = csr[j + q];
#pragma unroll
        for (int q = 0; q < 4; ++q) v[q] = *(const u32*)&In[(size_t)(e[q] & 0xffff) * 256 + c];
#pragma unroll
        for (int q = 0; q < 4; ++q) {
            float w = edge_w(e[q]);
            f32x2 p0 = __builtin_amdgcn_cvt_pk_f32_fp8(v[q], false);
            f32x2 p1 = __builtin_amdgcn_cvt_pk_f32_fp8(v[q], true);
            a0 = fmaf(w, p0.x, a0);
            a1 = fmaf(w, p0.y, a1);
            a2 = fmaf(w, p1.x, a2);
            a3 = fmaf(w, p1.y, a3);
        }
    }
    for (; j < r1; ++j) {
        u32 e = csr[j];
        u32 v = *(const u32*)&In[(size_t)(e & 0xffff) * 256 + c];
        float w = edge_w(e);
        f32x2 p0 = __builtin_amdgcn_cvt_pk_f32_fp8(v, false);
        f32x2 p1 = __builtin_amdgcn_cvt_pk_f32_fp8(v, true);
        a0 = fmaf(w, p0.x, a0);
        a1 = fmaf(w, p0.y, a1);
        a2 = fmaf(w, p1.x, a2);
        a3 = fmaf(w, p1.y, a3);
    }
    uint2 o;
    o.x = ((u32)f2bf(di * a1) << 16) | (u32)f2bf(di * a0);
    o.y = ((u32)f2bf(di * a3) << 16) | (u32)f2bf(di * a2);
    *(uint2*)&Out[(size_t)node * 256 + c] = o;
}

// ---------------------------------------------------------------------------
// MFMA GEMM layer 1: H1[M,256] = relu( A[M,128] @ W1 + b1 ), fp8 e4m3 out
// ---------------------------------------------------------------------------
template<int K>
__global__ __launch_bounds__(256, 3)
void gemm1_kernel(const u16* __restrict__ A, const short8* __restrict__ Bswz,
                  const float* __restrict__ bias, u8* __restrict__ Out, int M) {
    const int KS = K / 32;
    __shared__ u16 cst[64][264];
    int tid  = threadIdx.x;
    int wave = tid >> 6, lane = tid & 63;
    int m0 = blockIdx.x * 64;
    int n0 = wave * 64;
    int lr = lane & 15;
    int lk = (lane >> 4) * 8;

    f32x4 acc[4][4];
#pragma unroll
    for (int i = 0; i < 4; ++i)
#pragma unroll
        for (int j = 0; j < 4; ++j) acc[i][j] = {0.f, 0.f, 0.f, 0.f};

    for (int k0i = 0; k0i < KS; ++k0i) {
        int k0 = k0i * 32;
        short8 a[4], bh[4], bl[4];
#pragma unroll
        for (int mt = 0; mt < 4; ++mt) {
            int m = m0 + mt * 16 + lr;
            if (m > M - 1) m = M - 1;
            a[mt] = *(const short8*)&A[(size_t)m * K + k0 + lk];
        }
        const short8* bp = Bswz + ((size_t)(wave * KS + k0i) * 8) * 64 + lane;
#pragma unroll
        for (int nt = 0; nt < 4; ++nt) {
            bh[nt] = bp[(size_t)nt * 64];
            bl[nt] = bp[(size_t)(4 + nt) * 64];
        }
#pragma unroll
        for (int mt = 0; mt < 4; ++mt)
#pragma unroll
            for (int nt = 0; nt < 4; ++nt) {
                acc[mt][nt] = __builtin_amdgcn_mfma_f32_16x16x32_bf16(a[mt], bh[nt], acc[mt][nt], 0, 0, 0);
                acc[mt][nt] = __builtin_amdgcn_mfma_f32_16x16x32_bf16(a[mt], bl[nt], acc[mt][nt], 0, 0, 0);
            }
    }

#pragma unroll
    for (int mt = 0; mt < 4; ++mt)
#pragma unroll
        for (int nt = 0; nt < 4; ++nt) {
            int col = n0 + nt * 16 + lr;
            float b = bias[col];
#pragma unroll
            for (int r = 0; r < 4; ++r) {
                int row = mt * 16 + (lane >> 4) * 4 + r;
                cst[row][col] = f2bf(fmaxf(acc[mt][nt][r] + b, 0.f));
            }
        }
    __syncthreads();
#pragma unroll
    for (int p = 0; p < 8; ++p) {
        int row = p * 8 + (tid >> 5);
        int c16 = (tid & 31) * 8;
        int m = m0 + row;
        if (m < M) {
            uint4 v = *(const uint4*)&cst[row][c16];
            uint2 o = make_uint2(pack4_fp8(v.x, v.y), pack4_fp8(v.z, v.w));
            *(uint2*)&Out[(size_t)m * 256 + c16] = o;
        }
    }
}

// ---------------------------------------------------------------------------
// MFMA GEMM layer 2 + fused mean-pool
// ---------------------------------------------------------------------------
__global__ __launch_bounds__(256, 3)
void gemm2_pool_kernel(const u16* __restrict__ A, const short8* __restrict__ Bswz,
                       const float* __restrict__ bias, const int* __restrict__ batch,
                       float* __restrict__ pooled, int M) {
    const int K = H_DIM, KS = K / 32;
    __shared__ u16 cst[64][264];
    __shared__ int batch_s[64];
    int tid  = threadIdx.x;
    int wave = tid >> 6, lane = tid & 63;
    int m0 = blockIdx.x * 64;
    int n0 = wave * 64;
    int lr = lane & 15;
    int lk = (lane >> 4) * 8;

    f32x4 acc[4][4];
#pragma unroll
    for (int i = 0; i < 4; ++i)
#pragma unroll
        for (int j = 0; j < 4; ++j) acc[i][j] = {0.f, 0.f, 0.f, 0.f};

    for (int k0i = 0; k0i < KS; ++k0i) {
        int k0 = k0i * 32;
        short8 a[4], bh[4], bl[4];
#pragma unroll
        for (int mt = 0; mt < 4; ++mt) {
            int m = m0 + mt * 16 + lr;
            if (m > M - 1) m = M - 1;
            a[mt] = *(const short8*)&A[(size_t)m * K + k0 + lk];
        }
        const short8* bp = Bswz + ((size_t)(wave * KS + k0i) * 8) * 64 + lane;
#pragma unroll
        for (int nt = 0; nt < 4; ++nt) {
            bh[nt] = bp[(size_t)nt * 64];
            bl[nt] = bp[(size_t)(4 + nt) * 64];
        }
#pragma unroll
        for (int mt = 0; mt < 4; ++mt)
#pragma unroll
            for (int nt = 0; nt < 4; ++nt) {
                acc[mt][nt] = __builtin_amdgcn_mfma_f32_16x16x32_bf16(a[mt], bh[nt], acc[mt][nt], 0, 0, 0);
                acc[mt][nt] = __builtin_amdgcn_mfma_f32_16x16x32_bf16(a[mt], bl[nt], acc[mt][nt], 0, 0, 0);
            }
    }

    if (tid < 64) {
        int m = m0 + tid;
        batch_s[tid] = (m < M) ? batch[m] : -1;
    }
#pragma unroll
    for (int mt = 0; mt < 4; ++mt)
#pragma unroll
        for (int nt = 0; nt < 4; ++nt) {
            int col = n0 + nt * 16 + lr;
            float b = bias[col];
#pragma unroll
            for (int r = 0; r < 4; ++r) {
                int row = mt * 16 + (lane >> 4) * 4 + r;
                cst[row][col] = f2bf(fmaxf(acc[mt][nt][r] + b, 0.f));
            }
        }
    __syncthreads();

    // segmented pooling: thread = column, walk the 64 sorted rows
    int rows = M - m0; if (rows > 64) rows = 64;
    float s = 0.f;
    int gp = batch_s[0];
    for (int r = 0; r < rows; ++r) {
        int g = batch_s[r];
        if (g != gp) {
            atomicAdd(&pooled[(size_t)gp * H_DIM + tid], s);
            s = 0.f;
            gp = g;
        }
        s += bf2f(cst[r][tid]);
    }
    atomicAdd(&pooled[(size_t)gp * H_DIM + tid], s);
}

// ---------------------------------------------------------------------------
// Heads (fp32): h_graph = pooled/cnt (cnt from goff diffs); mu/logvar heads
// ---------------------------------------------------------------------------
__global__ void head_kernel(const float* __restrict__ pooled, const int* __restrict__ goff,
                            const float* __restrict__ Wmu, const float* __restrict__ bmu,
                            const float* __restrict__ Wlv, const float* __restrict__ blv,
                            float* __restrict__ out) {
    __shared__ float hg[H_DIM];
    int g = blockIdx.x, l = threadIdx.x;   // 64 threads
    float inv = 1.0f / fmaxf((float)(goff[g + 1] - goff[g]), 1.0f);
    for (int k = l; k < H_DIM; k += 64) hg[k] = pooled[(size_t)g * H_DIM + k] * inv;
    __syncthreads();
    float mu = bmu[l], lv = blv[l];
    for (int k = 0; k < H_DIM; ++k) {
        float h = hg[k];
        mu = fmaf(h, Wmu[k * L_DIM + l], mu);
        lv = fmaf(h, Wlv[k * L_DIM + l], lv);
    }
    out[(size_t)g * L_DIM + l] = mu;
    out[(size_t)G_NUM * L_DIM + (size_t)g * L_DIM + l] = lv;
}

// ---------------------------------------------------------------------------
extern "C" void kernel_launch(void* const* d_in, const int* in_sizes, int n_in,
                              void* d_out, int out_size, void* d_ws, size_t ws_size,
                              hipStream_t stream) {
    const float* x     = (const float*)d_in[0];
    const int*   ei    = (const int*)  d_in[1];
    const int*   batch = (const int*)  d_in[2];
    const float* W1  = (const float*)d_in[4];
    const float* b1  = (const float*)d_in[5];
    const float* W2  = (const float*)d_in[6];
    const float* b2  = (const float*)d_in[7];
    const float* Wmu = (const float*)d_in[8];
    const float* bmu = (const float*)d_in[9];
    const float* Wlv = (const float*)d_in[10];
    const float* blv = (const float*)d_in[11];
    const int* src = ei;
    const int* dst = ei + N_EDGES;

    char* ws = (char*)d_ws;
    size_t off = 0;
    auto alloc = [&](size_t bytes) -> void* {
        void* p = ws + off;
        off += (bytes + 255) & ~(size_t)255;
        return p;
    };
    // hist + pooled adjacent -> one memset clears both
    int*   hist     = (int*)alloc((size_t)N_NODES * 4);
    float* pooled   = (float*)alloc((size_t)G_NUM * H_DIM * 4);
    float* dinv     = (float*)alloc((size_t)N_NODES * 4);
    int*   row_ptr  = (int*)alloc((size_t)(N_NODES + 1) * 4);
    int*   bcur     = (int*)alloc((size_t)NBUCK * CUR_STRIDE * 4);
    u32*   csr      = (u32*)alloc((size_t)N_EDGES * 4);
    uint2* binrec   = (uint2*)alloc((size_t)N_EDGES * 8);   // 6.4 MB
    int*   excl     = (int*)alloc((size_t)N_NODES * 4);
    int*   partials = (int*)alloc(256 * 4);
    int*   goff     = (int*)alloc((size_t)(G_NUM + 1) * 4);
    u16*   xb    = (u16*)alloc((size_t)N_NODES * F_IN_D * 2);  // 12.8 MB
    u16*   Xa    = (u16*)alloc((size_t)N_NODES * F_IN_D * 2);  // 12.8 MB
    u8*    H8    = (u8*)alloc((size_t)N_NODES * H_DIM);        // 12.8 MB (fp8)
    u16*   Ha    = (u16*)alloc((size_t)N_NODES * H_DIM * 2);   // 25.6 MB
    u16*   w1swz = (u16*)alloc((size_t)2 * F_IN_D * H_DIM * 2);
    u16*   w2swz = (u16*)alloc((size_t)2 * H_DIM * H_DIM * 2);
    (void)ws_size; (void)n_in; (void)in_sizes; (void)out_size;

    const int GEMM_NB = (N_NODES + 63) / 64;     // 782
    size_t zero_bytes = (size_t)((char*)(pooled + G_NUM * H_DIM) - (char*)hist);

    hipMemsetAsync(hist, 0, zero_bytes, stream);
    prep_kernel<<<NB_COUNT + NB_SCAN + NB_CONV, 256, 0, stream>>>(
        dst, hist, batch, goff, x, xb, W1, w1swz, W2, w2swz);
    scan_chunk_kernel<<<NB_SCAN, 256, 0, stream>>>(hist, excl, partials, dinv, N_NODES);
    scan_final_kernel<<<NB_SCAN, 256, 0, stream>>>(excl, partials, row_ptr, bcur, N_NODES, NB_SCAN);
    bin_kernel<<<BIN_NB, 256, 0, stream>>>(src, dst, dinv, bcur, binrec);
    grp_kernel<<<NBUCK, 256, 0, stream>>>(row_ptr, binrec, csr);

    // layer 1: aggregate(x) then GEMM  (A_hat (X W) == (A_hat X) W)
    agg128_kernel<<<(N_NODES + 3) / 4, 256, 0, stream>>>(xb, dinv, row_ptr, csr, Xa);
    gemm1_kernel<F_IN_D><<<GEMM_NB, 256, 0, stream>>>(Xa, (const short8*)w1swz, b1, H8, N_NODES);
    // layer 2: aggregate(H1 fp8) then GEMM with fused mean-pool
    agg256_fp8_kernel<<<(N_NODES + 3) / 4, 256, 0, stream>>>(H8, dinv, row_ptr, csr, Ha);
    gemm2_pool_kernel<<<GEMM_NB, 256, 0, stream>>>(Ha, (const short8*)w2swz, b2, batch, pooled, N_NODES);

    head_kernel<<<G_NUM, 64, 0, stream>>>(pooled, goff, Wmu, bmu, Wlv, blv, (float*)d_out);
}

// Round 6
// 266.342 us; speedup vs baseline: 1.2076x; 1.1202x over previous
//
#include <hip/hip_runtime.h>
#include <hip/hip_fp16.h>

// Problem constants (from the reference file)
#define N_NODES 50000
#define N_EDGES 800000
#define F_IN_D  128
#define H_DIM   256
#define L_DIM   64
#define G_NUM   500

typedef unsigned int   u32;
typedef unsigned short u16;
typedef unsigned char  u8;
typedef __attribute__((ext_vector_type(8))) short short8;
typedef __attribute__((ext_vector_type(4))) float f32x4;
typedef __attribute__((ext_vector_type(2))) float f32x2;

// bucket = dst >> 8 (256 nodes per bucket)
#define BSHIFT 8
#define NBUCK ((N_NODES + 255) >> BSHIFT)          // 196
#define CUR_STRIDE 16                               // 1 counter / 64B line
#define BIN_NB 512
#define EPB ((N_EDGES + BIN_NB - 1) / BIN_NB)       // 1563 edges per bin block
#define BUCK_CAP 8192                               // fixed slab per bucket (mean 4096, max ~4400)

static __device__ __forceinline__ float bf2f(u16 u) {
    union { u32 i; float f; } x; x.i = ((u32)u) << 16; return x.f;
}
static __device__ __forceinline__ u16 f2bf(float f) {
    union { float f; u32 i; } x; x.f = f;
    u32 r = (x.i + 0x7fffu + ((x.i >> 16) & 1u)) >> 16;
    return (u16)r;
}
// csr entry: src node in low 16 bits (N_NODES < 65536), fp16(dinv[src]) in high 16
static __device__ __forceinline__ float edge_w(u32 e) {
    return __half2float(__ushort_as_half((u16)(e >> 16)));
}

// pack two bf16-pairs (4 values) into 4 fp8 e4m3 bytes via HW converter
static __device__ __forceinline__ u32 pack4_fp8(u32 a, u32 b) {
    u32 w = __builtin_amdgcn_cvt_pk_fp8_f32(bf2f((u16)(a & 0xffff)),
                                            bf2f((u16)(a >> 16)), 0, false);
    w = __builtin_amdgcn_cvt_pk_fp8_f32(bf2f((u16)(b & 0xffff)),
                                        bf2f((u16)(b >> 16)), w, true);
    return w;
}

// B-swizzle address (in u16 units): fragment layout for mfma_16x16x32_bf16.
static __device__ __forceinline__ u32 bswz_idx(int n, int k, int plane, int KS) {
    int n0g = n >> 6, nt = (n >> 4) & 3, lr = n & 15;
    int k0i = k >> 5, ks = k & 31, lq = ks >> 3, j = ks & 7;
    return ((u32)((((n0g * KS + k0i) * 2 + plane) * 4 + nt) * 64 + lq * 16 + lr)) * 8 + j;
}

// ---------------------------------------------------------------------------
// Fused preprocessing: batch bounds + all dtype conversions + slab cursor init.
// (Degree counting moved to cnt_kernel's LDS histograms — the 800k random
// global atomics were prep's 27MB write amplification and ~70% of its time.)
// ---------------------------------------------------------------------------
#define NXQ (N_NODES * F_IN_D / 4)          // 1,600,000
#define NW1 (F_IN_D * H_DIM)                // 32,768
#define NW2 (H_DIM * H_DIM)                 // 65,536
#define NB_SCAN  ((N_NODES + 255) / 256)            // 196
#define NB_CONV  ((NXQ + NW1 + NW2 + 255) / 256)    // 6634

__global__ void prep_kernel(const int* __restrict__ batch, int* __restrict__ goff,
                            const float* __restrict__ x, u16* __restrict__ xb,
                            const float* __restrict__ W1, u16* __restrict__ w1swz,
                            const float* __restrict__ W2, u16* __restrict__ w2swz,
                            int* __restrict__ bcur) {
    int b = blockIdx.x;
    if (b < NB_SCAN) {
        int i = b * 256 + threadIdx.x;
        if (i >= N_NODES) return;
        int v = batch[i];
        if (i == 0) {
            for (int g = 0; g <= v; ++g) goff[g] = 0;
        } else {
            int p = batch[i - 1];
            for (int g = p + 1; g <= v; ++g) goff[g] = i;
        }
        if (i == N_NODES - 1) {
            for (int g = v + 1; g <= G_NUM; ++g) goff[g] = N_NODES;
        }
    } else if (b < NB_SCAN + NB_CONV) {
        int i = (b - NB_SCAN) * 256 + threadIdx.x;
        if (i < NXQ) {
            float4 v = *(const float4*)&x[(size_t)i * 4];
            ushort4 o;
            o.x = f2bf(v.x); o.y = f2bf(v.y); o.z = f2bf(v.z); o.w = f2bf(v.w);
            *(ushort4*)&xb[(size_t)i * 4] = o;
        } else if (i < NXQ + NW1) {
            int idx = i - NXQ;
            int k = idx >> 8, n = idx & 255;
            float w = W1[idx];
            u16 h = f2bf(w);
            w1swz[bswz_idx(n, k, 0, F_IN_D / 32)] = h;
            w1swz[bswz_idx(n, k, 1, F_IN_D / 32)] = f2bf(w - bf2f(h));
        } else if (i < NXQ + NW1 + NW2) {
            int idx = i - NXQ - NW1;
            int k = idx >> 8, n = idx & 255;
            float w = W2[idx];
            u16 h = f2bf(w);
            w2swz[bswz_idx(n, k, 0, H_DIM / 32)] = h;
            w2swz[bswz_idx(n, k, 1, H_DIM / 32)] = f2bf(w - bf2f(h));
        }
    } else {
        // init per-bucket slab cursors to fixed-stride bases
        int t = threadIdx.x;
        if (t < NBUCK) bcur[t * CUR_STRIDE] = t * BUCK_CAP;
    }
}

// exclusive scan of hist (chunk=256) + fused dinv computation
__global__ void scan_chunk_kernel(const int* __restrict__ in, int* __restrict__ excl,
                                  int* __restrict__ partials, float* __restrict__ dinv, int n) {
    __shared__ int sm[256];
    int t = threadIdx.x;
    int i = blockIdx.x * 256 + t;
    int v = (i < n) ? in[i] : 0;
    sm[t] = v; __syncthreads();
    for (int off = 1; off < 256; off <<= 1) {
        int x = (t >= off) ? sm[t - off] : 0;
        __syncthreads();
        sm[t] += x;
        __syncthreads();
    }
    if (i < n) {
        excl[i] = sm[t] - v;
        dinv[i] = 1.0f / sqrtf((float)(v + 1));   // +1 self loop
    }
    if (t == 255) partials[blockIdx.x] = sm[255];
}

__global__ void scan_final_kernel(const int* __restrict__ excl, const int* __restrict__ partials,
                                  int* __restrict__ out, int n, int nb) {
    __shared__ int sm[256];
    int t = threadIdx.x;
    int v = (t < nb) ? partials[t] : 0;
    sm[t] = v; __syncthreads();
    for (int off = 1; off < 256; off <<= 1) {
        int x = (t >= off) ? sm[t - off] : 0;
        __syncthreads();
        sm[t] += x;
        __syncthreads();
    }
    int pre = (blockIdx.x > 0) ? sm[blockIdx.x - 1] : 0;   // uniform read
    int i = blockIdx.x * 256 + t;
    if (i < n) out[i] = excl[i] + pre;
    if (blockIdx.x == (unsigned)(nb - 1) && t == 0) out[n] = sm[nb - 1];
}

// ---------------------------------------------------------------------------
// CSR build, pass 1 (bin): per-block counting sort into 196 fixed-stride
// bucket slabs. Compact u32 records (src:16 | dst&255:16). No dependency on
// degrees/row_ptr -> degree counting can use the slabs (LDS, no global atomics).
// ---------------------------------------------------------------------------
__global__ __launch_bounds__(256)
void bin_kernel(const int* __restrict__ src, const int* __restrict__ dst,
                int* __restrict__ bcur, u32* __restrict__ binrec) {
    __shared__ int lhist[NBUCK];
    __shared__ int lbase[NBUCK];
    int t = threadIdx.x;
    int e0 = blockIdx.x * EPB;
    int e1 = e0 + EPB; if (e1 > N_EDGES) e1 = N_EDGES;
    for (int i = t; i < NBUCK; i += 256) lhist[i] = 0;
    __syncthreads();
    for (int e = e0 + t; e < e1; e += 256)
        atomicAdd(&lhist[dst[e] >> BSHIFT], 1);
    __syncthreads();
    for (int i = t; i < NBUCK; i += 256) {
        int c = lhist[i];
        lbase[i] = c ? atomicAdd(&bcur[i * CUR_STRIDE], c) : 0;
        lhist[i] = 0;   // reuse as running rank cursor
    }
    __syncthreads();
    for (int e = e0 + t; e < e1; e += 256) {
        int d = dst[e], s = src[e];
        int bkt = d >> BSHIFT;
        int rank = atomicAdd(&lhist[bkt], 1);
        binrec[(size_t)lbase[bkt] + rank] = (u32)s | ((u32)(d & 255) << 16);
    }
}

// ---------------------------------------------------------------------------
// Degree count: one block per bucket, LDS histogram over its 256 nodes from
// the slab, coalesced write to hist. Replaces 800k random global atomics.
// ---------------------------------------------------------------------------
__global__ __launch_bounds__(256)
void cnt_kernel(const int* __restrict__ bcur, const u32* __restrict__ binrec,
                int* __restrict__ hist) {
    __shared__ int lh[256];
    int b = blockIdx.x;
    int t = threadIdx.x;
    lh[t] = 0;
    __syncthreads();
    int s0 = b * BUCK_CAP;
    int s1 = bcur[b * CUR_STRIDE];   // base + count after bin
    for (int p = s0 + t; p < s1; p += 256)
        atomicAdd(&lh[(binrec[p] >> 16) & 255], 1);
    __syncthreads();
    int n = (b << BSHIFT) + t;
    if (n < N_NODES) hist[n] = lh[t];
}

// ---------------------------------------------------------------------------
// CSR build, pass 2 (place): one block per bucket streams its slab and
// scatters final entries within its 16KB csr window via LDS node cursors.
// dinv[s] random reads are L2-resident (200KB).
// ---------------------------------------------------------------------------
__global__ __launch_bounds__(256)
void place2_kernel(const int* __restrict__ rp, const int* __restrict__ bcur,
                   const u32* __restrict__ binrec, const float* __restrict__ dinv,
                   u32* __restrict__ csr) {
    __shared__ int ncur[256];
    int b = blockIdx.x;
    int t = threadIdx.x;
    int n0 = b << BSHIFT;
    int n1 = n0 + 256; if (n1 > N_NODES) n1 = N_NODES;
    if (n0 + t < n1) ncur[t] = rp[n0 + t];
    __syncthreads();
    int s0 = b * BUCK_CAP;
    int s1 = bcur[b * CUR_STRIDE];
    for (int p = s0 + t; p < s1; p += 256) {
        u32 r = binrec[p];
        int s = (int)(r & 0xffff);
        int pos = atomicAdd(&ncur[(r >> 16) & 255], 1);
        u32 w = (u32)__half_as_ushort(__float2half(dinv[s]));
        csr[pos] = (u32)s | (w << 16);
    }
}

// ---------------------------------------------------------------------------
// GCN aggregation layer 1, bf16 in -> bf16 out. One wave per node.
// ---------------------------------------------------------------------------
__global__ __launch_bounds__(256)
void agg128_kernel(const u16* __restrict__ In, const float* __restrict__ dinv,
                   const int* __restrict__ rp, const u32* __restrict__ csr,
                   u16* __restrict__ Out) {
    int node = blockIdx.x * 4 + (threadIdx.x >> 6);
    int lane = threadIdx.x & 63;
    if (node >= N_NODES) return;
    int c = lane * 2;
    float di = dinv[node];
    int r0 = rp[node], r1 = rp[node + 1];
    u32 sv = *(const u32*)&In[(size_t)node * 128 + c];
    float a0 = di * bf2f((u16)(sv & 0xffff));
    float a1 = di * bf2f((u16)(sv >> 16));
    int j = r0;
    for (; j + 8 <= r1; j += 8) {
        u32 e[8];
        u32 v[8];
#pragma unroll
        for (int q = 0; q < 8; ++q) e[q] = csr[j + q];
#pragma unroll
        for (int q = 0; q < 8; ++q) v[q] = *(const u32*)&In[(size_t)(e[q] & 0xffff) * 128 + c];
#pragma unroll
        for (int q = 0; q < 8; ++q) {
            float w = edge_w(e[q]);
            a0 = fmaf(w, bf2f((u16)(v[q] & 0xffff)), a0);
            a1 = fmaf(w, bf2f((u16)(v[q] >> 16)), a1);
        }
    }
    for (; j + 4 <= r1; j += 4) {
        u32 e[4];
        u32 v[4];
#pragma unroll
        for (int q = 0; q < 4; ++q) e[q] = csr[j + q];
#pragma unroll
        for (int q = 0; q < 4; ++q) v[q] = *(const u32*)&In[(size_t)(e[q] & 0xffff) * 128 + c];
#pragma unroll
        for (int q = 0; q < 4; ++q) {
            float w = edge_w(e[q]);
            a0 = fmaf(w, bf2f((u16)(v[q] & 0xffff)), a0);
            a1 = fmaf(w, bf2f((u16)(v[q] >> 16)), a1);
        }
    }
    for (; j < r1; ++j) {
        u32 e = csr[j];
        u32 v = *(const u32*)&In[(size_t)(e & 0xffff) * 128 + c];
        float w = edge_w(e);
        a0 = fmaf(w, bf2f((u16)(v & 0xffff)), a0);
        a1 = fmaf(w, bf2f((u16)(v >> 16)), a1);
    }
    u32 o = ((u32)f2bf(di * a1) << 16) | (u32)f2bf(di * a0);
    *(u32*)&Out[(size_t)node * 128 + c] = o;
}

// ---------------------------------------------------------------------------
// GCN aggregation layer 2, fp8 e4m3 in -> bf16 out. One wave per node.
// ---------------------------------------------------------------------------
__global__ __launch_bounds__(256)
void agg256_fp8_kernel(const u8* __restrict__ In, const float* __restrict__ dinv,
                       const int* __restrict__ rp, const u32* __restrict__ csr,
                       u16* __restrict__ Out) {
    int node = blockIdx.x * 4 + (threadIdx.x >> 6);
    int lane = threadIdx.x & 63;
    if (node >= N_NODES) return;
    int c = lane * 4;
    float di = dinv[node];
    int r0 = rp[node], r1 = rp[node + 1];
    u32 sv = *(const u32*)&In[(size_t)node * 256 + c];
    f32x2 s01 = __builtin_amdgcn_cvt_pk_f32_fp8(sv, false);
    f32x2 s23 = __builtin_amdgcn_cvt_pk_f32_fp8(sv, true);
    float a0 = di * s01.x;
    float a1 = di * s01.y;
    float a2 = di * s23.x;
    float a3 = di * s23.y;
    int j = r0;
    for (; j + 8 <= r1; j += 8) {
        u32 e[8];
        u32 v[8];
#pragma unroll
        for (int q = 0; q < 8; ++q) e[q] = csr[j + q];
#pragma unroll
        for (int q = 0; q < 8; ++q) v[q] = *(const u32*)&In[(size_t)(e[q] & 0xffff) * 256 + c];
#pragma unroll
        for (int q = 0; q < 8; ++q) {
            float w = edge_w(e[q]);
            f32x2 p0 = __builtin_amdgcn_cvt_pk_f32_fp8(v[q], false);
            f32x2 p1 = __builtin_amdgcn_cvt_pk_f32_fp8(v[q], true);
            a0 = fmaf(w, p0.x, a0);
            a1 = fmaf(w, p0.y, a1);
            a2 = fmaf(w, p1.x, a2);
            a3 = fmaf(w, p1.y, a3);
        }
    }
    for (; j + 4 <= r1; j += 4) {
        u32 e[4];
        u32 v[4];
#pragma unroll
        for (int q = 0; q < 4; ++q) e[q] = csr[j + q];
#pragma unroll
        for (int q = 0; q < 4; ++q) v[q] = *(const u32*)&In[(size_t)(e[q] & 0xffff) * 256 + c];
#pragma unroll
        for (int q = 0; q < 4; ++q) {
            float w = edge_w(e[q]);
            f32x2 p0 = __builtin_amdgcn_cvt_pk_f32_fp8(v[q], false);
            f32x2 p1 = __builtin_amdgcn_cvt_pk_f32_fp8(v[q], true);
            a0 = fmaf(w, p0.x, a0);
            a1 = fmaf(w, p0.y, a1);
            a2 = fmaf(w, p1.x, a2);
            a3 = fmaf(w, p1.y, a3);
        }
    }
    for (; j < r1; ++j) {
        u32 e = csr[j];
        u32 v = *(const u32*)&In[(size_t)(e & 0xffff) * 256 + c];
        float w = edge_w(e);
        f32x2 p0 = __builtin_amdgcn_cvt_pk_f32_fp8(v, false);
        f32x2 p1 = __builtin_amdgcn_cvt_pk_f32_fp8(v, true);
        a0 = fmaf(w, p0.x, a0);
        a1 = fmaf(w, p0.y, a1);
        a2 = fmaf(w, p1.x, a2);
        a3 = fmaf(w, p1.y, a3);
    }
    uint2 o;
    o.x = ((u32)f2bf(di * a1) << 16) | (u32)f2bf(di * a0);
    o.y = ((u32)f2bf(di * a3) << 16) | (u32)f2bf(di * a2);
    *(uint2*)&Out[(size_t)node * 256 + c] = o;
}

// ---------------------------------------------------------------------------
// MFMA GEMM layer 1: H1[M,256] = relu( A[M,128] @ W1 + b1 ), fp8 e4m3 out
// ---------------------------------------------------------------------------
template<int K>
__global__ __launch_bounds__(256, 3)
void gemm1_kernel(const u16* __restrict__ A, const short8* __restrict__ Bswz,
                  const float* __restrict__ bias, u8* __restrict__ Out, int M) {
    const int KS = K / 32;
    __shared__ u16 cst[64][264];
    int tid  = threadIdx.x;
    int wave = tid >> 6, lane = tid & 63;
    int m0 = blockIdx.x * 64;
    int n0 = wave * 64;
    int lr = lane & 15;
    int lk = (lane >> 4) * 8;

    f32x4 acc[4][4];
#pragma unroll
    for (int i = 0; i < 4; ++i)
#pragma unroll
        for (int j = 0; j < 4; ++j) acc[i][j] = {0.f, 0.f, 0.f, 0.f};

    for (int k0i = 0; k0i < KS; ++k0i) {
        int k0 = k0i * 32;
        short8 a[4], bh[4], bl[4];
#pragma unroll
        for (int mt = 0; mt < 4; ++mt) {
            int m = m0 + mt * 16 + lr;
            if (m > M - 1) m = M - 1;
            a[mt] = *(const short8*)&A[(size_t)m * K + k0 + lk];
        }
        const short8* bp = Bswz + ((size_t)(wave * KS + k0i) * 8) * 64 + lane;
#pragma unroll
        for (int nt = 0; nt < 4; ++nt) {
            bh[nt] = bp[(size_t)nt * 64];
            bl[nt] = bp[(size_t)(4 + nt) * 64];
        }
#pragma unroll
        for (int mt = 0; mt < 4; ++mt)
#pragma unroll
            for (int nt = 0; nt < 4; ++nt) {
                acc[mt][nt] = __builtin_amdgcn_mfma_f32_16x16x32_bf16(a[mt], bh[nt], acc[mt][nt], 0, 0, 0);
                acc[mt][nt] = __builtin_amdgcn_mfma_f32_16x16x32_bf16(a[mt], bl[nt], acc[mt][nt], 0, 0, 0);
            }
    }

#pragma unroll
    for (int mt = 0; mt < 4; ++mt)
#pragma unroll
        for (int nt = 0; nt < 4; ++nt) {
            int col = n0 + nt * 16 + lr;
            float b = bias[col];
#pragma unroll
            for (int r = 0; r < 4; ++r) {
                int row = mt * 16 + (lane >> 4) * 4 + r;
                cst[row][col] = f2bf(fmaxf(acc[mt][nt][r] + b, 0.f));
            }
        }
    __syncthreads();
#pragma unroll
    for (int p = 0; p < 8; ++p) {
        int row = p * 8 + (tid >> 5);
        int c16 = (tid & 31) * 8;
        int m = m0 + row;
        if (m < M) {
            uint4 v = *(const uint4*)&cst[row][c16];
            uint2 o = make_uint2(pack4_fp8(v.x, v.y), pack4_fp8(v.z, v.w));
            *(uint2*)&Out[(size_t)m * 256 + c16] = o;
        }
    }
}

// ---------------------------------------------------------------------------
// MFMA GEMM layer 2 + fused mean-pool
// ---------------------------------------------------------------------------
__global__ __launch_bounds__(256, 3)
void gemm2_pool_kernel(const u16* __restrict__ A, const short8* __restrict__ Bswz,
                       const float* __restrict__ bias, const int* __restrict__ batch,
                       float* __restrict__ pooled, int M) {
    const int K = H_DIM, KS = K / 32;
    __shared__ u16 cst[64][264];
    __shared__ int batch_s[64];
    int tid  = threadIdx.x;
    int wave = tid >> 6, lane = tid & 63;
    int m0 = blockIdx.x * 64;
    int n0 = wave * 64;
    int lr = lane & 15;
    int lk = (lane >> 4) * 8;

    f32x4 acc[4][4];
#pragma unroll
    for (int i = 0; i < 4; ++i)
#pragma unroll
        for (int j = 0; j < 4; ++j) acc[i][j] = {0.f, 0.f, 0.f, 0.f};

    for (int k0i = 0; k0i < KS; ++k0i) {
        int k0 = k0i * 32;
        short8 a[4], bh[4], bl[4];
#pragma unroll
        for (int mt = 0; mt < 4; ++mt) {
            int m = m0 + mt * 16 + lr;
            if (m > M - 1) m = M - 1;
            a[mt] = *(const short8*)&A[(size_t)m * K + k0 + lk];
        }
        const short8* bp = Bswz + ((size_t)(wave * KS + k0i) * 8) * 64 + lane;
#pragma unroll
        for (int nt = 0; nt < 4; ++nt) {
            bh[nt] = bp[(size_t)nt * 64];
            bl[nt] = bp[(size_t)(4 + nt) * 64];
        }
#pragma unroll
        for (int mt = 0; mt < 4; ++mt)
#pragma unroll
            for (int nt = 0; nt < 4; ++nt) {
                acc[mt][nt] = __builtin_amdgcn_mfma_f32_16x16x32_bf16(a[mt], bh[nt], acc[mt][nt], 0, 0, 0);
                acc[mt][nt] = __builtin_amdgcn_mfma_f32_16x16x32_bf16(a[mt], bl[nt], acc[mt][nt], 0, 0, 0);
            }
    }

    if (tid < 64) {
        int m = m0 + tid;
        batch_s[tid] = (m < M) ? batch[m] : -1;
    }
#pragma unroll
    for (int mt = 0; mt < 4; ++mt)
#pragma unroll
        for (int nt = 0; nt < 4; ++nt) {
            int col = n0 + nt * 16 + lr;
            float b = bias[col];
#pragma unroll
            for (int r = 0; r < 4; ++r) {
                int row = mt * 16 + (lane >> 4) * 4 + r;
                cst[row][col] = f2bf(fmaxf(acc[mt][nt][r] + b, 0.f));
            }
        }
    __syncthreads();

    // segmented pooling: thread = column, walk the 64 sorted rows
    int rows = M - m0; if (rows > 64) rows = 64;
    float s = 0.f;
    int gp = batch_s[0];
    for (int r = 0; r < rows; ++r) {
        int g = batch_s[r];
        if (g != gp) {
            atomicAdd(&pooled[(size_t)gp * H_DIM + tid], s);
            s = 0.f;
            gp = g;
        }
        s += bf2f(cst[r][tid]);
    }
    atomicAdd(&pooled[(size_t)gp * H_DIM + tid], s);
}

// ---------------------------------------------------------------------------
// Heads (fp32): h_graph = pooled/cnt (cnt from goff diffs); mu/logvar heads
// ---------------------------------------------------------------------------
__global__ void head_kernel(const float* __restrict__ pooled, const int* __restrict__ goff,
                            const float* __restrict__ Wmu, const float* __restrict__ bmu,
                            const float* __restrict__ Wlv, const float* __restrict__ blv,
                            float* __restrict__ out) {
    __shared__ float hg[H_DIM];
    int g = blockIdx.x, l = threadIdx.x;   // 64 threads
    float inv = 1.0f / fmaxf((float)(goff[g + 1] - goff[g]), 1.0f);
    for (int k = l; k < H_DIM; k += 64) hg[k] = pooled[(size_t)g * H_DIM + k] * inv;
    __syncthreads();
    float mu = bmu[l], lv = blv[l];
    for (int k = 0; k < H_DIM; ++k) {
        float h = hg[k];
        mu = fmaf(h, Wmu[k * L_DIM + l], mu);
        lv = fmaf(h, Wlv[k * L_DIM + l], lv);
    }
    out[(size_t)g * L_DIM + l] = mu;
    out[(size_t)G_NUM * L_DIM + (size_t)g * L_DIM + l] = lv;
}

// ---------------------------------------------------------------------------
extern "C" void kernel_launch(void* const* d_in, const int* in_sizes, int n_in,
                              void* d_out, int out_size, void* d_ws, size_t ws_size,
                              hipStream_t stream) {
    const float* x     = (const float*)d_in[0];
    const int*   ei    = (const int*)  d_in[1];
    const int*   batch = (const int*)  d_in[2];
    const float* W1  = (const float*)d_in[4];
    const float* b1  = (const float*)d_in[5];
    const float* W2  = (const float*)d_in[6];
    const float* b2  = (const float*)d_in[7];
    const float* Wmu = (const float*)d_in[8];
    const float* bmu = (const float*)d_in[9];
    const float* Wlv = (const float*)d_in[10];
    const float* blv = (const float*)d_in[11];
    const int* src = ei;
    const int* dst = ei + N_EDGES;

    char* ws = (char*)d_ws;
    size_t off = 0;
    auto alloc = [&](size_t bytes) -> void* {
        void* p = ws + off;
        off += (bytes + 255) & ~(size_t)255;
        return p;
    };
    float* pooled   = (float*)alloc((size_t)G_NUM * H_DIM * 4);
    int*   hist     = (int*)alloc((size_t)N_NODES * 4);
    float* dinv     = (float*)alloc((size_t)N_NODES * 4);
    int*   row_ptr  = (int*)alloc((size_t)(N_NODES + 1) * 4);
    int*   bcur     = (int*)alloc((size_t)NBUCK * CUR_STRIDE * 4);
    u32*   csr      = (u32*)alloc((size_t)N_EDGES * 4);
    u32*   binrec   = (u32*)alloc((size_t)NBUCK * BUCK_CAP * 4);  // 6.4 MB
    int*   excl     = (int*)alloc((size_t)N_NODES * 4);
    int*   partials = (int*)alloc(256 * 4);
    int*   goff     = (int*)alloc((size_t)(G_NUM + 1) * 4);
    u16*   xb    = (u16*)alloc((size_t)N_NODES * F_IN_D * 2);  // 12.8 MB
    u16*   Xa    = (u16*)alloc((size_t)N_NODES * F_IN_D * 2);  // 12.8 MB
    u8*    H8    = (u8*)alloc((size_t)N_NODES * H_DIM);        // 12.8 MB (fp8)
    u16*   Ha    = (u16*)alloc((size_t)N_NODES * H_DIM * 2);   // 25.6 MB
    u16*   w1swz = (u16*)alloc((size_t)2 * F_IN_D * H_DIM * 2);
    u16*   w2swz = (u16*)alloc((size_t)2 * H_DIM * H_DIM * 2);
    (void)ws_size; (void)n_in; (void)in_sizes; (void)out_size;

    const int GEMM_NB = (N_NODES + 63) / 64;     // 782

    // only pooled needs zeroing now (hist fully overwritten by cnt_kernel)
    hipMemsetAsync(pooled, 0, (size_t)G_NUM * H_DIM * 4, stream);
    prep_kernel<<<NB_SCAN + NB_CONV + 1, 256, 0, stream>>>(
        batch, goff, x, xb, W1, w1swz, W2, w2swz, bcur);
    bin_kernel<<<BIN_NB, 256, 0, stream>>>(src, dst, bcur, binrec);
    cnt_kernel<<<NBUCK, 256, 0, stream>>>(bcur, binrec, hist);
    scan_chunk_kernel<<<NB_SCAN, 256, 0, stream>>>(hist, excl, partials, dinv, N_NODES);
    scan_final_kernel<<<NB_SCAN, 256, 0, stream>>>(excl, partials, row_ptr, N_NODES, NB_SCAN);
    place2_kernel<<<NBUCK, 256, 0, stream>>>(row_ptr, bcur, binrec, dinv, csr);

    // layer 1: aggregate(x) then GEMM  (A_hat (X W) == (A_hat X) W)
    agg128_kernel<<<(N_NODES + 3) / 4, 256, 0, stream>>>(xb, dinv, row_ptr, csr, Xa);
    gemm1_kernel<F_IN_D><<<GEMM_NB, 256, 0, stream>>>(Xa, (const short8*)w1swz, b1, H8, N_NODES);
    // layer 2: aggregate(H1 fp8) then GEMM with fused mean-pool
    agg256_fp8_kernel<<<(N_NODES + 3) / 4, 256, 0, stream>>>(H8, dinv, row_ptr, csr, Ha);
    gemm2_pool_kernel<<<GEMM_NB, 256, 0, stream>>>(Ha, (const short8*)w2swz, b2, batch, pooled, N_NODES);

    head_kernel<<<G_NUM, 64, 0, stream>>>(pooled, goff, Wmu, bmu, Wlv, blv, (float*)d_out);
}

// Round 7
// 255.686 us; speedup vs baseline: 1.2580x; 1.0417x over previous
//
#include <hip/hip_runtime.h>
#include <hip/hip_fp16.h>

// Problem constants (from the reference file)
#define N_NODES 50000
#define N_EDGES 800000
#define F_IN_D  128
#define H_DIM   256
#define L_DIM   64
#define G_NUM   500

typedef unsigned int   u32;
typedef unsigned short u16;
typedef unsigned char  u8;
typedef __attribute__((ext_vector_type(8))) short short8;
typedef __attribute__((ext_vector_type(4))) float f32x4;
typedef __attribute__((ext_vector_type(2))) float f32x2;

// bucket = dst >> 8 (256 nodes per bucket)
#define BSHIFT 8
#define NBUCK ((N_NODES + 255) >> BSHIFT)          // 196
#define CUR_STRIDE 16                               // 1 counter / 64B line
#define BIN_NB 512
#define EPB ((N_EDGES + BIN_NB - 1) / BIN_NB)       // 1563 edges per bin block
#define BUCK_CAP 8192                               // fixed slab per bucket (mean 4096, max ~4400)

static __device__ __forceinline__ float bf2f(u16 u) {
    union { u32 i; float f; } x; x.i = ((u32)u) << 16; return x.f;
}
static __device__ __forceinline__ u16 f2bf(float f) {
    union { float f; u32 i; } x; x.f = f;
    u32 r = (x.i + 0x7fffu + ((x.i >> 16) & 1u)) >> 16;
    return (u16)r;
}
// csr entry: src node in low 16 bits (N_NODES < 65536), fp16(dinv[src]) in high 16
static __device__ __forceinline__ float edge_w(u32 e) {
    return __half2float(__ushort_as_half((u16)(e >> 16)));
}

// pack two bf16-pairs (4 values) into 4 fp8 e4m3 bytes via HW converter
static __device__ __forceinline__ u32 pack4_fp8(u32 a, u32 b) {
    u32 w = __builtin_amdgcn_cvt_pk_fp8_f32(bf2f((u16)(a & 0xffff)),
                                            bf2f((u16)(a >> 16)), 0, false);
    w = __builtin_amdgcn_cvt_pk_fp8_f32(bf2f((u16)(b & 0xffff)),
                                        bf2f((u16)(b >> 16)), w, true);
    return w;
}

// B-swizzle address (in u16 units): fragment layout for mfma_16x16x32_bf16.
static __device__ __forceinline__ u32 bswz_idx(int n, int k, int plane, int KS) {
    int n0g = n >> 6, nt = (n >> 4) & 3, lr = n & 15;
    int k0i = k >> 5, ks = k & 31, lq = ks >> 3, j = ks & 7;
    return ((u32)((((n0g * KS + k0i) * 2 + plane) * 4 + nt) * 64 + lq * 16 + lr)) * 8 + j;
}

// ---------------------------------------------------------------------------
// Fused preprocessing: CSR bin pass + batch bounds + all dtype conversions.
// Bin blocks first so their slab scatter overlaps the conversion BW work.
// x converts to fp8 e4m3 (layer-1 gather is scattered-load-path-bound; halving
// bytes/edge halved agg time when applied to layer 2 in earlier rounds).
// ---------------------------------------------------------------------------
#define NXQ (N_NODES * F_IN_D / 4)          // 1,600,000
#define NW1 (F_IN_D * H_DIM)                // 32,768
#define NW2 (H_DIM * H_DIM)                 // 65,536
#define NB_SCAN  ((N_NODES + 255) / 256)            // 196
#define NB_CONV  ((NXQ + NW1 + NW2 + 255) / 256)    // 6634

__global__ void prep_kernel(const int* __restrict__ src, const int* __restrict__ dst,
                            const int* __restrict__ batch, int* __restrict__ goff,
                            const float* __restrict__ x, u8* __restrict__ xq,
                            const float* __restrict__ W1, u16* __restrict__ w1swz,
                            const float* __restrict__ W2, u16* __restrict__ w2swz,
                            int* __restrict__ bcur, u32* __restrict__ binrec) {
    int b = blockIdx.x;
    if (b < BIN_NB) {
        // CSR bin pass: per-block counting sort into 196 fixed-stride slabs.
        // bcur is zero-based (memset); slab base = bkt * BUCK_CAP.
        __shared__ int lhist[NBUCK];
        __shared__ int lbase[NBUCK];
        int t = threadIdx.x;
        int e0 = b * EPB;
        int e1 = e0 + EPB; if (e1 > N_EDGES) e1 = N_EDGES;
        for (int i = t; i < NBUCK; i += 256) lhist[i] = 0;
        __syncthreads();
        for (int e = e0 + t; e < e1; e += 256)
            atomicAdd(&lhist[dst[e] >> BSHIFT], 1);
        __syncthreads();
        for (int i = t; i < NBUCK; i += 256) {
            int c = lhist[i];
            lbase[i] = i * BUCK_CAP + (c ? atomicAdd(&bcur[i * CUR_STRIDE], c) : 0);
            lhist[i] = 0;   // reuse as running rank cursor
        }
        __syncthreads();
        for (int e = e0 + t; e < e1; e += 256) {
            int d = dst[e], s = src[e];
            int bkt = d >> BSHIFT;
            int rank = atomicAdd(&lhist[bkt], 1);
            binrec[(size_t)lbase[bkt] + rank] = (u32)s | ((u32)(d & 255) << 16);
        }
    } else if (b < BIN_NB + NB_SCAN) {
        int i = (b - BIN_NB) * 256 + threadIdx.x;
        if (i >= N_NODES) return;
        int v = batch[i];
        if (i == 0) {
            for (int g = 0; g <= v; ++g) goff[g] = 0;
        } else {
            int p = batch[i - 1];
            for (int g = p + 1; g <= v; ++g) goff[g] = i;
        }
        if (i == N_NODES - 1) {
            for (int g = v + 1; g <= G_NUM; ++g) goff[g] = N_NODES;
        }
    } else {
        int i = (b - BIN_NB - NB_SCAN) * 256 + threadIdx.x;
        if (i < NXQ) {
            float4 v = *(const float4*)&x[(size_t)i * 4];
            u32 w = __builtin_amdgcn_cvt_pk_fp8_f32(v.x, v.y, 0, false);
            w = __builtin_amdgcn_cvt_pk_fp8_f32(v.z, v.w, w, true);
            *(u32*)&xq[(size_t)i * 4] = w;
        } else if (i < NXQ + NW1) {
            int idx = i - NXQ;
            int k = idx >> 8, n = idx & 255;
            float w = W1[idx];
            u16 h = f2bf(w);
            w1swz[bswz_idx(n, k, 0, F_IN_D / 32)] = h;
            w1swz[bswz_idx(n, k, 1, F_IN_D / 32)] = f2bf(w - bf2f(h));
        } else if (i < NXQ + NW1 + NW2) {
            int idx = i - NXQ - NW1;
            int k = idx >> 8, n = idx & 255;
            float w = W2[idx];
            u16 h = f2bf(w);
            w2swz[bswz_idx(n, k, 0, H_DIM / 32)] = h;
            w2swz[bswz_idx(n, k, 1, H_DIM / 32)] = f2bf(w - bf2f(h));
        }
    }
}

// ---------------------------------------------------------------------------
// Degree count + chunk scan fused: chunk == bucket (256 nodes). LDS histogram
// from the slab feeds the LDS scan directly — no hist global round-trip.
// ---------------------------------------------------------------------------
__global__ __launch_bounds__(256)
void cnt_scan_kernel(const int* __restrict__ bcur, const u32* __restrict__ binrec,
                     int* __restrict__ excl, int* __restrict__ partials,
                     float* __restrict__ dinv) {
    __shared__ int lh[256];
    __shared__ int sm[256];
    int b = blockIdx.x;
    int t = threadIdx.x;
    lh[t] = 0;
    __syncthreads();
    int s0 = b * BUCK_CAP;
    int s1 = s0 + bcur[b * CUR_STRIDE];
    for (int p = s0 + t; p < s1; p += 256)
        atomicAdd(&lh[(binrec[p] >> 16) & 255], 1);
    __syncthreads();
    int i = (b << BSHIFT) + t;
    int v = lh[t];
    sm[t] = v; __syncthreads();
    for (int off = 1; off < 256; off <<= 1) {
        int x = (t >= off) ? sm[t - off] : 0;
        __syncthreads();
        sm[t] += x;
        __syncthreads();
    }
    if (i < N_NODES) {
        excl[i] = sm[t] - v;
        dinv[i] = 1.0f / sqrtf((float)(v + 1));   // +1 self loop
    }
    if (t == 255) partials[b] = sm[255];
}

__global__ void scan_final_kernel(const int* __restrict__ excl, const int* __restrict__ partials,
                                  int* __restrict__ out, int n, int nb) {
    __shared__ int sm[256];
    int t = threadIdx.x;
    int v = (t < nb) ? partials[t] : 0;
    sm[t] = v; __syncthreads();
    for (int off = 1; off < 256; off <<= 1) {
        int x = (t >= off) ? sm[t - off] : 0;
        __syncthreads();
        sm[t] += x;
        __syncthreads();
    }
    int pre = (blockIdx.x > 0) ? sm[blockIdx.x - 1] : 0;   // uniform read
    int i = blockIdx.x * 256 + t;
    if (i < n) out[i] = excl[i] + pre;
    if (blockIdx.x == (unsigned)(nb - 1) && t == 0) out[n] = sm[nb - 1];
}

// ---------------------------------------------------------------------------
// CSR build, pass 2 (place): one block per bucket streams its slab and
// scatters final entries within its 16KB csr window via LDS node cursors.
// ---------------------------------------------------------------------------
__global__ __launch_bounds__(256)
void place2_kernel(const int* __restrict__ rp, const int* __restrict__ bcur,
                   const u32* __restrict__ binrec, const float* __restrict__ dinv,
                   u32* __restrict__ csr) {
    __shared__ int ncur[256];
    int b = blockIdx.x;
    int t = threadIdx.x;
    int n0 = b << BSHIFT;
    int n1 = n0 + 256; if (n1 > N_NODES) n1 = N_NODES;
    if (n0 + t < n1) ncur[t] = rp[n0 + t];
    __syncthreads();
    int s0 = b * BUCK_CAP;
    int s1 = s0 + bcur[b * CUR_STRIDE];
    for (int p = s0 + t; p < s1; p += 256) {
        u32 r = binrec[p];
        int s = (int)(r & 0xffff);
        int pos = atomicAdd(&ncur[(r >> 16) & 255], 1);
        u32 w = (u32)__half_as_ushort(__float2half(dinv[s]));
        csr[pos] = (u32)s | (w << 16);
    }
}

// ---------------------------------------------------------------------------
// GCN aggregation layer 1, fp8 e4m3 in -> bf16 out. One wave per node.
// 128 B/edge gather (2 lines) — half the bf16 version's bytes at the
// scattered-load-path roofline.
// ---------------------------------------------------------------------------
__global__ __launch_bounds__(256)
void agg128_fp8_kernel(const u8* __restrict__ In, const float* __restrict__ dinv,
                       const int* __restrict__ rp, const u32* __restrict__ csr,
                       u16* __restrict__ Out) {
    int node = blockIdx.x * 4 + (threadIdx.x >> 6);
    int lane = threadIdx.x & 63;
    if (node >= N_NODES) return;
    int c = lane * 2;
    float di = dinv[node];
    int r0 = rp[node], r1 = rp[node + 1];
    u32 sv = *(const u16*)&In[(size_t)node * 128 + c];
    f32x2 s = __builtin_amdgcn_cvt_pk_f32_fp8(sv, false);
    float a0 = di * s.x;
    float a1 = di * s.y;
    int j = r0;
    for (; j + 8 <= r1; j += 8) {
        u32 e[8];
        u32 v[8];
#pragma unroll
        for (int q = 0; q < 8; ++q) e[q] = csr[j + q];
#pragma unroll
        for (int q = 0; q < 8; ++q) v[q] = *(const u16*)&In[(size_t)(e[q] & 0xffff) * 128 + c];
#pragma unroll
        for (int q = 0; q < 8; ++q) {
            float w = edge_w(e[q]);
            f32x2 p = __builtin_amdgcn_cvt_pk_f32_fp8(v[q], false);
            a0 = fmaf(w, p.x, a0);
            a1 = fmaf(w, p.y, a1);
        }
    }
    for (; j + 4 <= r1; j += 4) {
        u32 e[4];
        u32 v[4];
#pragma unroll
        for (int q = 0; q < 4; ++q) e[q] = csr[j + q];
#pragma unroll
        for (int q = 0; q < 4; ++q) v[q] = *(const u16*)&In[(size_t)(e[q] & 0xffff) * 128 + c];
#pragma unroll
        for (int q = 0; q < 4; ++q) {
            float w = edge_w(e[q]);
            f32x2 p = __builtin_amdgcn_cvt_pk_f32_fp8(v[q], false);
            a0 = fmaf(w, p.x, a0);
            a1 = fmaf(w, p.y, a1);
        }
    }
    for (; j < r1; ++j) {
        u32 e = csr[j];
        u32 v = *(const u16*)&In[(size_t)(e & 0xffff) * 128 + c];
        float w = edge_w(e);
        f32x2 p = __builtin_amdgcn_cvt_pk_f32_fp8(v, false);
        a0 = fmaf(w, p.x, a0);
        a1 = fmaf(w, p.y, a1);
    }
    u32 o = ((u32)f2bf(di * a1) << 16) | (u32)f2bf(di * a0);
    *(u32*)&Out[(size_t)node * 128 + c] = o;
}

// ---------------------------------------------------------------------------
// GCN aggregation layer 2, fp8 e4m3 in -> bf16 out. One wave per node.
// ---------------------------------------------------------------------------
__global__ __launch_bounds__(256)
void agg256_fp8_kernel(const u8* __restrict__ In, const float* __restrict__ dinv,
                       const int* __restrict__ rp, const u32* __restrict__ csr,
                       u16* __restrict__ Out) {
    int node = blockIdx.x * 4 + (threadIdx.x >> 6);
    int lane = threadIdx.x & 63;
    if (node >= N_NODES) return;
    int c = lane * 4;
    float di = dinv[node];
    int r0 = rp[node], r1 = rp[node + 1];
    u32 sv = *(const u32*)&In[(size_t)node * 256 + c];
    f32x2 s01 = __builtin_amdgcn_cvt_pk_f32_fp8(sv, false);
    f32x2 s23 = __builtin_amdgcn_cvt_pk_f32_fp8(sv, true);
    float a0 = di * s01.x;
    float a1 = di * s01.y;
    float a2 = di * s23.x;
    float a3 = di * s23.y;
    int j = r0;
    for (; j + 8 <= r1; j += 8) {
        u32 e[8];
        u32 v[8];
#pragma unroll
        for (int q = 0; q < 8; ++q) e[q] = csr[j + q];
#pragma unroll
        for (int q = 0; q < 8; ++q) v[q] = *(const u32*)&In[(size_t)(e[q] & 0xffff) * 256 + c];
#pragma unroll
        for (int q = 0; q < 8; ++q) {
            float w = edge_w(e[q]);
            f32x2 p0 = __builtin_amdgcn_cvt_pk_f32_fp8(v[q], false);
            f32x2 p1 = __builtin_amdgcn_cvt_pk_f32_fp8(v[q], true);
            a0 = fmaf(w, p0.x, a0);
            a1 = fmaf(w, p0.y, a1);
            a2 = fmaf(w, p1.x, a2);
            a3 = fmaf(w, p1.y, a3);
        }
    }
    for (; j + 4 <= r1; j += 4) {
        u32 e[4];
        u32 v[4];
#pragma unroll
        for (int q = 0; q < 4; ++q) e[q] = csr[j + q];
#pragma unroll
        for (int q = 0; q < 4; ++q) v[q] = *(const u32*)&In[(size_t)(e[q] & 0xffff) * 256 + c];
#pragma unroll
        for (int q = 0; q < 4; ++q) {
            float w = edge_w(e[q]);
            f32x2 p0 = __builtin_amdgcn_cvt_pk_f32_fp8(v[q], false);
            f32x2 p1 = __builtin_amdgcn_cvt_pk_f32_fp8(v[q], true);
            a0 = fmaf(w, p0.x, a0);
            a1 = fmaf(w, p0.y, a1);
            a2 = fmaf(w, p1.x, a2);
            a3 = fmaf(w, p1.y, a3);
        }
    }
    for (; j < r1; ++j) {
        u32 e = csr[j];
        u32 v = *(const u32*)&In[(size_t)(e & 0xffff) * 256 + c];
        float w = edge_w(e);
        f32x2 p0 = __builtin_amdgcn_cvt_pk_f32_fp8(v, false);
        f32x2 p1 = __builtin_amdgcn_cvt_pk_f32_fp8(v, true);
        a0 = fmaf(w, p0.x, a0);
        a1 = fmaf(w, p0.y, a1);
        a2 = fmaf(w, p1.x, a2);
        a3 = fmaf(w, p1.y, a3);
    }
    uint2 o;
    o.x = ((u32)f2bf(di * a1) << 16) | (u32)f2bf(di * a0);
    o.y = ((u32)f2bf(di * a3) << 16) | (u32)f2bf(di * a2);
    *(uint2*)&Out[(size_t)node * 256 + c] = o;
}

// ---------------------------------------------------------------------------
// MFMA GEMM layer 1: H1[M,256] = relu( A[M,128] @ W1 + b1 ), fp8 e4m3 out
// ---------------------------------------------------------------------------
template<int K>
__global__ __launch_bounds__(256, 3)
void gemm1_kernel(const u16* __restrict__ A, const short8* __restrict__ Bswz,
                  const float* __restrict__ bias, u8* __restrict__ Out, int M) {
    const int KS = K / 32;
    __shared__ u16 cst[64][264];
    int tid  = threadIdx.x;
    int wave = tid >> 6, lane = tid & 63;
    int m0 = blockIdx.x * 64;
    int n0 = wave * 64;
    int lr = lane & 15;
    int lk = (lane >> 4) * 8;

    f32x4 acc[4][4];
#pragma unroll
    for (int i = 0; i < 4; ++i)
#pragma unroll
        for (int j = 0; j < 4; ++j) acc[i][j] = {0.f, 0.f, 0.f, 0.f};

    for (int k0i = 0; k0i < KS; ++k0i) {
        int k0 = k0i * 32;
        short8 a[4], bh[4], bl[4];
#pragma unroll
        for (int mt = 0; mt < 4; ++mt) {
            int m = m0 + mt * 16 + lr;
            if (m > M - 1) m = M - 1;
            a[mt] = *(const short8*)&A[(size_t)m * K + k0 + lk];
        }
        const short8* bp = Bswz + ((size_t)(wave * KS + k0i) * 8) * 64 + lane;
#pragma unroll
        for (int nt = 0; nt < 4; ++nt) {
            bh[nt] = bp[(size_t)nt * 64];
            bl[nt] = bp[(size_t)(4 + nt) * 64];
        }
#pragma unroll
        for (int mt = 0; mt < 4; ++mt)
#pragma unroll
            for (int nt = 0; nt < 4; ++nt) {
                acc[mt][nt] = __builtin_amdgcn_mfma_f32_16x16x32_bf16(a[mt], bh[nt], acc[mt][nt], 0, 0, 0);
                acc[mt][nt] = __builtin_amdgcn_mfma_f32_16x16x32_bf16(a[mt], bl[nt], acc[mt][nt], 0, 0, 0);
            }
    }

#pragma unroll
    for (int mt = 0; mt < 4; ++mt)
#pragma unroll
        for (int nt = 0; nt < 4; ++nt) {
            int col = n0 + nt * 16 + lr;
            float b = bias[col];
#pragma unroll
            for (int r = 0; r < 4; ++r) {
                int row = mt * 16 + (lane >> 4) * 4 + r;
                cst[row][col] = f2bf(fmaxf(acc[mt][nt][r] + b, 0.f));
            }
        }
    __syncthreads();
#pragma unroll
    for (int p = 0; p < 8; ++p) {
        int row = p * 8 + (tid >> 5);
        int c16 = (tid & 31) * 8;
        int m = m0 + row;
        if (m < M) {
            uint4 v = *(const uint4*)&cst[row][c16];
            uint2 o = make_uint2(pack4_fp8(v.x, v.y), pack4_fp8(v.z, v.w));
            *(uint2*)&Out[(size_t)m * 256 + c16] = o;
        }
    }
}

// ---------------------------------------------------------------------------
// MFMA GEMM layer 2 + fused mean-pool
// ---------------------------------------------------------------------------
__global__ __launch_bounds__(256, 3)
void gemm2_pool_kernel(const u16* __restrict__ A, const short8* __restrict__ Bswz,
                       const float* __restrict__ bias, const int* __restrict__ batch,
                       float* __restrict__ pooled, int M) {
    const int K = H_DIM, KS = K / 32;
    __shared__ u16 cst[64][264];
    __shared__ int batch_s[64];
    int tid  = threadIdx.x;
    int wave = tid >> 6, lane = tid & 63;
    int m0 = blockIdx.x * 64;
    int n0 = wave * 64;
    int lr = lane & 15;
    int lk = (lane >> 4) * 8;

    f32x4 acc[4][4];
#pragma unroll
    for (int i = 0; i < 4; ++i)
#pragma unroll
        for (int j = 0; j < 4; ++j) acc[i][j] = {0.f, 0.f, 0.f, 0.f};

    for (int k0i = 0; k0i < KS; ++k0i) {
        int k0 = k0i * 32;
        short8 a[4], bh[4], bl[4];
#pragma unroll
        for (int mt = 0; mt < 4; ++mt) {
            int m = m0 + mt * 16 + lr;
            if (m > M - 1) m = M - 1;
            a[mt] = *(const short8*)&A[(size_t)m * K + k0 + lk];
        }
        const short8* bp = Bswz + ((size_t)(wave * KS + k0i) * 8) * 64 + lane;
#pragma unroll
        for (int nt = 0; nt < 4; ++nt) {
            bh[nt] = bp[(size_t)nt * 64];
            bl[nt] = bp[(size_t)(4 + nt) * 64];
        }
#pragma unroll
        for (int mt = 0; mt < 4; ++mt)
#pragma unroll
            for (int nt = 0; nt < 4; ++nt) {
                acc[mt][nt] = __builtin_amdgcn_mfma_f32_16x16x32_bf16(a[mt], bh[nt], acc[mt][nt], 0, 0, 0);
                acc[mt][nt] = __builtin_amdgcn_mfma_f32_16x16x32_bf16(a[mt], bl[nt], acc[mt][nt], 0, 0, 0);
            }
    }

    if (tid < 64) {
        int m = m0 + tid;
        batch_s[tid] = (m < M) ? batch[m] : -1;
    }
#pragma unroll
    for (int mt = 0; mt < 4; ++mt)
#pragma unroll
        for (int nt = 0; nt < 4; ++nt) {
            int col = n0 + nt * 16 + lr;
            float b = bias[col];
#pragma unroll
            for (int r = 0; r < 4; ++r) {
                int row = mt * 16 + (lane >> 4) * 4 + r;
                cst[row][col] = f2bf(fmaxf(acc[mt][nt][r] + b, 0.f));
            }
        }
    __syncthreads();

    // segmented pooling: thread = column, walk the 64 sorted rows
    int rows = M - m0; if (rows > 64) rows = 64;
    float s = 0.f;
    int gp = batch_s[0];
    for (int r = 0; r < rows; ++r) {
        int g = batch_s[r];
        if (g != gp) {
            atomicAdd(&pooled[(size_t)gp * H_DIM + tid], s);
            s = 0.f;
            gp = g;
        }
        s += bf2f(cst[r][tid]);
    }
    atomicAdd(&pooled[(size_t)gp * H_DIM + tid], s);
}

// ---------------------------------------------------------------------------
// Heads (fp32): h_graph = pooled/cnt (cnt from goff diffs); mu/logvar heads
// ---------------------------------------------------------------------------
__global__ void head_kernel(const float* __restrict__ pooled, const int* __restrict__ goff,
                            const float* __restrict__ Wmu, const float* __restrict__ bmu,
                            const float* __restrict__ Wlv, const float* __restrict__ blv,
                            float* __restrict__ out) {
    __shared__ float hg[H_DIM];
    int g = blockIdx.x, l = threadIdx.x;   // 64 threads
    float inv = 1.0f / fmaxf((float)(goff[g + 1] - goff[g]), 1.0f);
    for (int k = l; k < H_DIM; k += 64) hg[k] = pooled[(size_t)g * H_DIM + k] * inv;
    __syncthreads();
    float mu = bmu[l], lv = blv[l];
    for (int k = 0; k < H_DIM; ++k) {
        float h = hg[k];
        mu = fmaf(h, Wmu[k * L_DIM + l], mu);
        lv = fmaf(h, Wlv[k * L_DIM + l], lv);
    }
    out[(size_t)g * L_DIM + l] = mu;
    out[(size_t)G_NUM * L_DIM + (size_t)g * L_DIM + l] = lv;
}

// ---------------------------------------------------------------------------
extern "C" void kernel_launch(void* const* d_in, const int* in_sizes, int n_in,
                              void* d_out, int out_size, void* d_ws, size_t ws_size,
                              hipStream_t stream) {
    const float* x     = (const float*)d_in[0];
    const int*   ei    = (const int*)  d_in[1];
    const int*   batch = (const int*)  d_in[2];
    const float* W1  = (const float*)d_in[4];
    const float* b1  = (const float*)d_in[5];
    const float* W2  = (const float*)d_in[6];
    const float* b2  = (const float*)d_in[7];
    const float* Wmu = (const float*)d_in[8];
    const float* bmu = (const float*)d_in[9];
    const float* Wlv = (const float*)d_in[10];
    const float* blv = (const float*)d_in[11];
    const int* src = ei;
    const int* dst = ei + N_EDGES;

    char* ws = (char*)d_ws;
    size_t off = 0;
    auto alloc = [&](size_t bytes) -> void* {
        void* p = ws + off;
        off += (bytes + 255) & ~(size_t)255;
        return p;
    };
    // pooled + bcur adjacent -> one memset clears both
    float* pooled   = (float*)alloc((size_t)G_NUM * H_DIM * 4);
    int*   bcur     = (int*)alloc((size_t)NBUCK * CUR_STRIDE * 4);
    float* dinv     = (float*)alloc((size_t)N_NODES * 4);
    int*   row_ptr  = (int*)alloc((size_t)(N_NODES + 1) * 4);
    u32*   csr      = (u32*)alloc((size_t)N_EDGES * 4);
    u32*   binrec   = (u32*)alloc((size_t)NBUCK * BUCK_CAP * 4);  // 6.4 MB
    int*   excl     = (int*)alloc((size_t)N_NODES * 4);
    int*   partials = (int*)alloc(256 * 4);
    int*   goff     = (int*)alloc((size_t)(G_NUM + 1) * 4);
    u8*    xq    = (u8*)alloc((size_t)N_NODES * F_IN_D);       // 6.4 MB (fp8)
    u16*   Xa    = (u16*)alloc((size_t)N_NODES * F_IN_D * 2);  // 12.8 MB
    u8*    H8    = (u8*)alloc((size_t)N_NODES * H_DIM);        // 12.8 MB (fp8)
    u16*   Ha    = (u16*)alloc((size_t)N_NODES * H_DIM * 2);   // 25.6 MB
    u16*   w1swz = (u16*)alloc((size_t)2 * F_IN_D * H_DIM * 2);
    u16*   w2swz = (u16*)alloc((size_t)2 * H_DIM * H_DIM * 2);
    (void)ws_size; (void)n_in; (void)in_sizes; (void)out_size;

    const int GEMM_NB = (N_NODES + 63) / 64;     // 782
    size_t zero_bytes = (size_t)((char*)(bcur + NBUCK * CUR_STRIDE) - (char*)pooled);

    hipMemsetAsync(pooled, 0, zero_bytes, stream);
    prep_kernel<<<BIN_NB + NB_SCAN + NB_CONV, 256, 0, stream>>>(
        src, dst, batch, goff, x, xq, W1, w1swz, W2, w2swz, bcur, binrec);
    cnt_scan_kernel<<<NBUCK, 256, 0, stream>>>(bcur, binrec, excl, partials, dinv);
    scan_final_kernel<<<NB_SCAN, 256, 0, stream>>>(excl, partials, row_ptr, N_NODES, NB_SCAN);
    place2_kernel<<<NBUCK, 256, 0, stream>>>(row_ptr, bcur, binrec, dinv, csr);

    // layer 1: aggregate(x fp8) then GEMM  (A_hat (X W) == (A_hat X) W)
    agg128_fp8_kernel<<<(N_NODES + 3) / 4, 256, 0, stream>>>(xq, dinv, row_ptr, csr, Xa);
    gemm1_kernel<F_IN_D><<<GEMM_NB, 256, 0, stream>>>(Xa, (const short8*)w1swz, b1, H8, N_NODES);
    // layer 2: aggregate(H1 fp8) then GEMM with fused mean-pool
    agg256_fp8_kernel<<<(N_NODES + 3) / 4, 256, 0, stream>>>(H8, dinv, row_ptr, csr, Ha);
    gemm2_pool_kernel<<<GEMM_NB, 256, 0, stream>>>(Ha, (const short8*)w2swz, b2, batch, pooled, N_NODES);

    head_kernel<<<G_NUM, 64, 0, stream>>>(pooled, goff, Wmu, bmu, Wlv, blv, (float*)d_out);
}

// Round 8
// 249.766 us; speedup vs baseline: 1.2878x; 1.0237x over previous
//
#include <hip/hip_runtime.h>
#include <hip/hip_fp16.h>

// Problem constants (from the reference file)
#define N_NODES 50000
#define N_EDGES 800000
#define F_IN_D  128
#define H_DIM   256
#define L_DIM   64
#define G_NUM   500

typedef unsigned int   u32;
typedef unsigned short u16;
typedef unsigned char  u8;
typedef __attribute__((ext_vector_type(8))) short short8;
typedef __attribute__((ext_vector_type(4))) float f32x4;
typedef __attribute__((ext_vector_type(2))) float f32x2;

// bucket = dst >> 8 (256 nodes per bucket)
#define BSHIFT 8
#define NBUCK ((N_NODES + 255) >> BSHIFT)          // 196
#define CUR_STRIDE 16                               // 1 counter / 64B line
#define BIN_NB 512
#define EPB ((N_EDGES + BIN_NB - 1) / BIN_NB)       // 1563 edges per bin block
#define BUCK_CAP 8192                               // fixed slab per bucket (mean 4096, max ~4400)

static __device__ __forceinline__ float bf2f(u16 u) {
    union { u32 i; float f; } x; x.i = ((u32)u) << 16; return x.f;
}
static __device__ __forceinline__ u16 f2bf(float f) {
    union { float f; u32 i; } x; x.f = f;
    u32 r = (x.i + 0x7fffu + ((x.i >> 16) & 1u)) >> 16;
    return (u16)r;
}
// csr entry: src node in low 16 bits (N_NODES < 65536), fp16(dinv[src]) in high 16
static __device__ __forceinline__ float edge_w(u32 e) {
    return __half2float(__ushort_as_half((u16)(e >> 16)));
}

// pack two bf16-pairs (4 values) into 4 fp8 e4m3 bytes via HW converter
static __device__ __forceinline__ u32 pack4_fp8(u32 a, u32 b) {
    u32 w = __builtin_amdgcn_cvt_pk_fp8_f32(bf2f((u16)(a & 0xffff)),
                                            bf2f((u16)(a >> 16)), 0, false);
    w = __builtin_amdgcn_cvt_pk_fp8_f32(bf2f((u16)(b & 0xffff)),
                                        bf2f((u16)(b >> 16)), w, true);
    return w;
}

// two f32 -> packed bf16x2 (HW, exact for fp8-sourced values)
static __device__ __forceinline__ u32 pkbf16(float lo, float hi) {
    u32 r;
    asm("v_cvt_pk_bf16_f32 %0, %1, %2" : "=v"(r) : "v"(lo), "v"(hi));
    return r;
}
// 8 fp8 e4m3 bytes -> short8 of bf16 (exact: fp8 ⊂ bf16)
static __device__ __forceinline__ short8 unpack8_fp8_bf16(uint2 v) {
    f32x2 p0 = __builtin_amdgcn_cvt_pk_f32_fp8(v.x, false);
    f32x2 p1 = __builtin_amdgcn_cvt_pk_f32_fp8(v.x, true);
    f32x2 p2 = __builtin_amdgcn_cvt_pk_f32_fp8(v.y, false);
    f32x2 p3 = __builtin_amdgcn_cvt_pk_f32_fp8(v.y, true);
    union { u32 w[4]; short8 s; } u;
    u.w[0] = pkbf16(p0.x, p0.y);
    u.w[1] = pkbf16(p1.x, p1.y);
    u.w[2] = pkbf16(p2.x, p2.y);
    u.w[3] = pkbf16(p3.x, p3.y);
    return u.s;
}

// B-swizzle address (in u16 units): fragment layout for mfma_16x16x32_bf16.
static __device__ __forceinline__ u32 bswz_idx(int n, int k, int plane, int KS) {
    int n0g = n >> 6, nt = (n >> 4) & 3, lr = n & 15;
    int k0i = k >> 5, ks = k & 31, lq = ks >> 3, j = ks & 7;
    return ((u32)((((n0g * KS + k0i) * 2 + plane) * 4 + nt) * 64 + lq * 16 + lr)) * 8 + j;
}

// ---------------------------------------------------------------------------
// Fused preprocessing: CSR bin pass + batch bounds + all dtype conversions.
// ---------------------------------------------------------------------------
#define NXQ (N_NODES * F_IN_D / 4)          // 1,600,000
#define NW1 (F_IN_D * H_DIM)                // 32,768
#define NW2 (H_DIM * H_DIM)                 // 65,536
#define NB_SCAN  ((N_NODES + 255) / 256)            // 196
#define NB_CONV  ((NXQ + NW1 + NW2 + 255) / 256)    // 6634

__global__ void prep_kernel(const int* __restrict__ src, const int* __restrict__ dst,
                            const int* __restrict__ batch, int* __restrict__ goff,
                            const float* __restrict__ x, u8* __restrict__ xq,
                            const float* __restrict__ W1, u16* __restrict__ w1swz,
                            const float* __restrict__ W2, u16* __restrict__ w2swz,
                            int* __restrict__ bcur, u32* __restrict__ binrec) {
    int b = blockIdx.x;
    if (b < BIN_NB) {
        // CSR bin pass: per-block counting sort into 196 fixed-stride slabs.
        __shared__ int lhist[NBUCK];
        __shared__ int lbase[NBUCK];
        int t = threadIdx.x;
        int e0 = b * EPB;
        int e1 = e0 + EPB; if (e1 > N_EDGES) e1 = N_EDGES;
        for (int i = t; i < NBUCK; i += 256) lhist[i] = 0;
        __syncthreads();
        for (int e = e0 + t; e < e1; e += 256)
            atomicAdd(&lhist[dst[e] >> BSHIFT], 1);
        __syncthreads();
        for (int i = t; i < NBUCK; i += 256) {
            int c = lhist[i];
            lbase[i] = i * BUCK_CAP + (c ? atomicAdd(&bcur[i * CUR_STRIDE], c) : 0);
            lhist[i] = 0;   // reuse as running rank cursor
        }
        __syncthreads();
        for (int e = e0 + t; e < e1; e += 256) {
            int d = dst[e], s = src[e];
            int bkt = d >> BSHIFT;
            int rank = atomicAdd(&lhist[bkt], 1);
            binrec[(size_t)lbase[bkt] + rank] = (u32)s | ((u32)(d & 255) << 16);
        }
    } else if (b < BIN_NB + NB_SCAN) {
        int i = (b - BIN_NB) * 256 + threadIdx.x;
        if (i >= N_NODES) return;
        int v = batch[i];
        if (i == 0) {
            for (int g = 0; g <= v; ++g) goff[g] = 0;
        } else {
            int p = batch[i - 1];
            for (int g = p + 1; g <= v; ++g) goff[g] = i;
        }
        if (i == N_NODES - 1) {
            for (int g = v + 1; g <= G_NUM; ++g) goff[g] = N_NODES;
        }
    } else {
        int i = (b - BIN_NB - NB_SCAN) * 256 + threadIdx.x;
        if (i < NXQ) {
            float4 v = *(const float4*)&x[(size_t)i * 4];
            u32 w = __builtin_amdgcn_cvt_pk_fp8_f32(v.x, v.y, 0, false);
            w = __builtin_amdgcn_cvt_pk_fp8_f32(v.z, v.w, w, true);
            *(u32*)&xq[(size_t)i * 4] = w;
        } else if (i < NXQ + NW1) {
            int idx = i - NXQ;
            int k = idx >> 8, n = idx & 255;
            float w = W1[idx];
            u16 h = f2bf(w);
            w1swz[bswz_idx(n, k, 0, F_IN_D / 32)] = h;
            w1swz[bswz_idx(n, k, 1, F_IN_D / 32)] = f2bf(w - bf2f(h));
        } else if (i < NXQ + NW1 + NW2) {
            int idx = i - NXQ - NW1;
            int k = idx >> 8, n = idx & 255;
            float w = W2[idx];
            u16 h = f2bf(w);
            w2swz[bswz_idx(n, k, 0, H_DIM / 32)] = h;
            w2swz[bswz_idx(n, k, 1, H_DIM / 32)] = f2bf(w - bf2f(h));
        }
    }
}

// ---------------------------------------------------------------------------
// Degree count + chunk scan fused: chunk == bucket (256 nodes).
// ---------------------------------------------------------------------------
__global__ __launch_bounds__(256)
void cnt_scan_kernel(const int* __restrict__ bcur, const u32* __restrict__ binrec,
                     int* __restrict__ excl, int* __restrict__ partials,
                     float* __restrict__ dinv) {
    __shared__ int lh[256];
    __shared__ int sm[256];
    int b = blockIdx.x;
    int t = threadIdx.x;
    lh[t] = 0;
    __syncthreads();
    int s0 = b * BUCK_CAP;
    int s1 = s0 + bcur[b * CUR_STRIDE];
    for (int p = s0 + t; p < s1; p += 256)
        atomicAdd(&lh[(binrec[p] >> 16) & 255], 1);
    __syncthreads();
    int i = (b << BSHIFT) + t;
    int v = lh[t];
    sm[t] = v; __syncthreads();
    for (int off = 1; off < 256; off <<= 1) {
        int x = (t >= off) ? sm[t - off] : 0;
        __syncthreads();
        sm[t] += x;
        __syncthreads();
    }
    if (i < N_NODES) {
        excl[i] = sm[t] - v;
        dinv[i] = 1.0f / sqrtf((float)(v + 1));   // +1 self loop
    }
    if (t == 255) partials[b] = sm[255];
}

// ---------------------------------------------------------------------------
// CSR build pass 2 + final scan fused: each block redundantly scans the 196
// partials in LDS (cheap), derives its bucket's prefix, writes row_ptr, and
// scatters final csr entries within its 16KB window via LDS node cursors.
// ---------------------------------------------------------------------------
__global__ __launch_bounds__(256)
void place2_kernel(const int* __restrict__ excl, const int* __restrict__ partials,
                   const int* __restrict__ bcur, const u32* __restrict__ binrec,
                   const float* __restrict__ dinv,
                   int* __restrict__ rp, u32* __restrict__ csr) {
    __shared__ int sm[256];
    __shared__ int ncur[256];
    int b = blockIdx.x;
    int t = threadIdx.x;
    int v = (t < NBUCK) ? partials[t] : 0;
    sm[t] = v; __syncthreads();
    for (int off = 1; off < 256; off <<= 1) {
        int x = (t >= off) ? sm[t - off] : 0;
        __syncthreads();
        sm[t] += x;
        __syncthreads();
    }
    int pre = (b > 0) ? sm[b - 1] : 0;   // uniform read
    int n0 = b << BSHIFT;
    int i = n0 + t;
    if (i < N_NODES) {
        int base = excl[i] + pre;
        rp[i] = base;
        ncur[t] = base;
    }
    if (b == NBUCK - 1 && t == 0) rp[N_NODES] = sm[NBUCK - 1];
    __syncthreads();
    int s0 = b * BUCK_CAP;
    int s1 = s0 + bcur[b * CUR_STRIDE];
    for (int p = s0 + t; p < s1; p += 256) {
        u32 r = binrec[p];
        int s = (int)(r & 0xffff);
        int pos = atomicAdd(&ncur[(r >> 16) & 255], 1);
        u32 w = (u32)__half_as_ushort(__float2half(dinv[s]));
        csr[pos] = (u32)s | (w << 16);
    }
}

// ---------------------------------------------------------------------------
// GCN aggregation layer 1, fp8 e4m3 in -> bf16 out. One wave per node.
// 16-deep main loop for memory-level parallelism.
// ---------------------------------------------------------------------------
__global__ __launch_bounds__(256)
void agg128_fp8_kernel(const u8* __restrict__ In, const float* __restrict__ dinv,
                       const int* __restrict__ rp, const u32* __restrict__ csr,
                       u16* __restrict__ Out) {
    int node = blockIdx.x * 4 + (threadIdx.x >> 6);
    int lane = threadIdx.x & 63;
    if (node >= N_NODES) return;
    int c = lane * 2;
    float di = dinv[node];
    int r0 = rp[node], r1 = rp[node + 1];
    u32 sv = *(const u16*)&In[(size_t)node * 128 + c];
    f32x2 s = __builtin_amdgcn_cvt_pk_f32_fp8(sv, false);
    float a0 = di * s.x;
    float a1 = di * s.y;
    int j = r0;
    for (; j + 16 <= r1; j += 16) {
        u32 e[16];
        u32 v[16];
#pragma unroll
        for (int q = 0; q < 16; ++q) e[q] = csr[j + q];
#pragma unroll
        for (int q = 0; q < 16; ++q) v[q] = *(const u16*)&In[(size_t)(e[q] & 0xffff) * 128 + c];
#pragma unroll
        for (int q = 0; q < 16; ++q) {
            float w = edge_w(e[q]);
            f32x2 p = __builtin_amdgcn_cvt_pk_f32_fp8(v[q], false);
            a0 = fmaf(w, p.x, a0);
            a1 = fmaf(w, p.y, a1);
        }
    }
    for (; j + 4 <= r1; j += 4) {
        u32 e[4];
        u32 v[4];
#pragma unroll
        for (int q = 0; q < 4; ++q) e[q] = csr[j + q];
#pragma unroll
        for (int q = 0; q < 4; ++q) v[q] = *(const u16*)&In[(size_t)(e[q] & 0xffff) * 128 + c];
#pragma unroll
        for (int q = 0; q < 4; ++q) {
            float w = edge_w(e[q]);
            f32x2 p = __builtin_amdgcn_cvt_pk_f32_fp8(v[q], false);
            a0 = fmaf(w, p.x, a0);
            a1 = fmaf(w, p.y, a1);
        }
    }
    for (; j < r1; ++j) {
        u32 e = csr[j];
        u32 v = *(const u16*)&In[(size_t)(e & 0xffff) * 128 + c];
        float w = edge_w(e);
        f32x2 p = __builtin_amdgcn_cvt_pk_f32_fp8(v, false);
        a0 = fmaf(w, p.x, a0);
        a1 = fmaf(w, p.y, a1);
    }
    u32 o = ((u32)f2bf(di * a1) << 16) | (u32)f2bf(di * a0);
    *(u32*)&Out[(size_t)node * 128 + c] = o;
}

// ---------------------------------------------------------------------------
// GCN aggregation layer 2, fp8 e4m3 in -> fp8 e4m3 out. One wave per node.
// fp8 output halves the Ha stream (gemm2 unpacks exactly to bf16).
// ---------------------------------------------------------------------------
__global__ __launch_bounds__(256)
void agg256_fp8_kernel(const u8* __restrict__ In, const float* __restrict__ dinv,
                       const int* __restrict__ rp, const u32* __restrict__ csr,
                       u8* __restrict__ Out) {
    int node = blockIdx.x * 4 + (threadIdx.x >> 6);
    int lane = threadIdx.x & 63;
    if (node >= N_NODES) return;
    int c = lane * 4;
    float di = dinv[node];
    int r0 = rp[node], r1 = rp[node + 1];
    u32 sv = *(const u32*)&In[(size_t)node * 256 + c];
    f32x2 s01 = __builtin_amdgcn_cvt_pk_f32_fp8(sv, false);
    f32x2 s23 = __builtin_amdgcn_cvt_pk_f32_fp8(sv, true);
    float a0 = di * s01.x;
    float a1 = di * s01.y;
    float a2 = di * s23.x;
    float a3 = di * s23.y;
    int j = r0;
    for (; j + 16 <= r1; j += 16) {
        u32 e[16];
        u32 v[16];
#pragma unroll
        for (int q = 0; q < 16; ++q) e[q] = csr[j + q];
#pragma unroll
        for (int q = 0; q < 16; ++q) v[q] = *(const u32*)&In[(size_t)(e[q] & 0xffff) * 256 + c];
#pragma unroll
        for (int q = 0; q < 16; ++q) {
            float w = edge_w(e[q]);
            f32x2 p0 = __builtin_amdgcn_cvt_pk_f32_fp8(v[q], false);
            f32x2 p1 = __builtin_amdgcn_cvt_pk_f32_fp8(v[q], true);
            a0 = fmaf(w, p0.x, a0);
            a1 = fmaf(w, p0.y, a1);
            a2 = fmaf(w, p1.x, a2);
            a3 = fmaf(w, p1.y, a3);
        }
    }
    for (; j + 4 <= r1; j += 4) {
        u32 e[4];
        u32 v[4];
#pragma unroll
        for (int q = 0; q < 4; ++q) e[q] = csr[j + q];
#pragma unroll
        for (int q = 0; q < 4; ++q) v[q] = *(const u32*)&In[(size_t)(e[q] & 0xffff) * 256 + c];
#pragma unroll
        for (int q = 0; q < 4; ++q) {
            float w = edge_w(e[q]);
            f32x2 p0 = __builtin_amdgcn_cvt_pk_f32_fp8(v[q], false);
            f32x2 p1 = __builtin_amdgcn_cvt_pk_f32_fp8(v[q], true);
            a0 = fmaf(w, p0.x, a0);
            a1 = fmaf(w, p0.y, a1);
            a2 = fmaf(w, p1.x, a2);
            a3 = fmaf(w, p1.y, a3);
        }
    }
    for (; j < r1; ++j) {
        u32 e = csr[j];
        u32 v = *(const u32*)&In[(size_t)(e & 0xffff) * 256 + c];
        float w = edge_w(e);
        f32x2 p0 = __builtin_amdgcn_cvt_pk_f32_fp8(v, false);
        f32x2 p1 = __builtin_amdgcn_cvt_pk_f32_fp8(v, true);
        a0 = fmaf(w, p0.x, a0);
        a1 = fmaf(w, p0.y, a1);
        a2 = fmaf(w, p1.x, a2);
        a3 = fmaf(w, p1.y, a3);
    }
    u32 o = __builtin_amdgcn_cvt_pk_fp8_f32(di * a0, di * a1, 0, false);
    o = __builtin_amdgcn_cvt_pk_fp8_f32(di * a2, di * a3, o, true);
    *(u32*)&Out[(size_t)node * 256 + c] = o;
}

// ---------------------------------------------------------------------------
// MFMA GEMM layer 1: H1[M,256] = relu( A[M,128] @ W1 + b1 ), fp8 e4m3 out
// ---------------------------------------------------------------------------
template<int K>
__global__ __launch_bounds__(256, 3)
void gemm1_kernel(const u16* __restrict__ A, const short8* __restrict__ Bswz,
                  const float* __restrict__ bias, u8* __restrict__ Out, int M) {
    const int KS = K / 32;
    __shared__ u16 cst[64][264];
    int tid  = threadIdx.x;
    int wave = tid >> 6, lane = tid & 63;
    int m0 = blockIdx.x * 64;
    int n0 = wave * 64;
    int lr = lane & 15;
    int lk = (lane >> 4) * 8;

    f32x4 acc[4][4];
#pragma unroll
    for (int i = 0; i < 4; ++i)
#pragma unroll
        for (int j = 0; j < 4; ++j) acc[i][j] = {0.f, 0.f, 0.f, 0.f};

    for (int k0i = 0; k0i < KS; ++k0i) {
        int k0 = k0i * 32;
        short8 a[4], bh[4], bl[4];
#pragma unroll
        for (int mt = 0; mt < 4; ++mt) {
            int m = m0 + mt * 16 + lr;
            if (m > M - 1) m = M - 1;
            a[mt] = *(const short8*)&A[(size_t)m * K + k0 + lk];
        }
        const short8* bp = Bswz + ((size_t)(wave * KS + k0i) * 8) * 64 + lane;
#pragma unroll
        for (int nt = 0; nt < 4; ++nt) {
            bh[nt] = bp[(size_t)nt * 64];
            bl[nt] = bp[(size_t)(4 + nt) * 64];
        }
#pragma unroll
        for (int mt = 0; mt < 4; ++mt)
#pragma unroll
            for (int nt = 0; nt < 4; ++nt) {
                acc[mt][nt] = __builtin_amdgcn_mfma_f32_16x16x32_bf16(a[mt], bh[nt], acc[mt][nt], 0, 0, 0);
                acc[mt][nt] = __builtin_amdgcn_mfma_f32_16x16x32_bf16(a[mt], bl[nt], acc[mt][nt], 0, 0, 0);
            }
    }

#pragma unroll
    for (int mt = 0; mt < 4; ++mt)
#pragma unroll
        for (int nt = 0; nt < 4; ++nt) {
            int col = n0 + nt * 16 + lr;
            float b = bias[col];
#pragma unroll
            for (int r = 0; r < 4; ++r) {
                int row = mt * 16 + (lane >> 4) * 4 + r;
                cst[row][col] = f2bf(fmaxf(acc[mt][nt][r] + b, 0.f));
            }
        }
    __syncthreads();
#pragma unroll
    for (int p = 0; p < 8; ++p) {
        int row = p * 8 + (tid >> 5);
        int c16 = (tid & 31) * 8;
        int m = m0 + row;
        if (m < M) {
            uint4 v = *(const uint4*)&cst[row][c16];
            uint2 o = make_uint2(pack4_fp8(v.x, v.y), pack4_fp8(v.z, v.w));
            *(uint2*)&Out[(size_t)m * 256 + c16] = o;
        }
    }
}

// ---------------------------------------------------------------------------
// MFMA GEMM layer 2 + fused mean-pool. A-operand is fp8 e4m3 (exact unpack
// to bf16 via HW cvt chain — fp8 values are exactly representable in bf16).
// ---------------------------------------------------------------------------
__global__ __launch_bounds__(256, 3)
void gemm2_pool_kernel(const u8* __restrict__ A, const short8* __restrict__ Bswz,
                       const float* __restrict__ bias, const int* __restrict__ batch,
                       float* __restrict__ pooled, int M) {
    const int K = H_DIM, KS = K / 32;
    __shared__ u16 cst[64][264];
    __shared__ int batch_s[64];
    int tid  = threadIdx.x;
    int wave = tid >> 6, lane = tid & 63;
    int m0 = blockIdx.x * 64;
    int n0 = wave * 64;
    int lr = lane & 15;
    int lk = (lane >> 4) * 8;

    f32x4 acc[4][4];
#pragma unroll
    for (int i = 0; i < 4; ++i)
#pragma unroll
        for (int j = 0; j < 4; ++j) acc[i][j] = {0.f, 0.f, 0.f, 0.f};

    for (int k0i = 0; k0i < KS; ++k0i) {
        int k0 = k0i * 32;
        short8 a[4], bh[4], bl[4];
#pragma unroll
        for (int mt = 0; mt < 4; ++mt) {
            int m = m0 + mt * 16 + lr;
            if (m > M - 1) m = M - 1;
            uint2 araw = *(const uint2*)&A[(size_t)m * K + k0 + lk];
            a[mt] = unpack8_fp8_bf16(araw);
        }
        const short8* bp = Bswz + ((size_t)(wave * KS + k0i) * 8) * 64 + lane;
#pragma unroll
        for (int nt = 0; nt < 4; ++nt) {
            bh[nt] = bp[(size_t)nt * 64];
            bl[nt] = bp[(size_t)(4 + nt) * 64];
        }
#pragma unroll
        for (int mt = 0; mt < 4; ++mt)
#pragma unroll
            for (int nt = 0; nt < 4; ++nt) {
                acc[mt][nt] = __builtin_amdgcn_mfma_f32_16x16x32_bf16(a[mt], bh[nt], acc[mt][nt], 0, 0, 0);
                acc[mt][nt] = __builtin_amdgcn_mfma_f32_16x16x32_bf16(a[mt], bl[nt], acc[mt][nt], 0, 0, 0);
            }
    }

    if (tid < 64) {
        int m = m0 + tid;
        batch_s[tid] = (m < M) ? batch[m] : -1;
    }
#pragma unroll
    for (int mt = 0; mt < 4; ++mt)
#pragma unroll
        for (int nt = 0; nt < 4; ++nt) {
            int col = n0 + nt * 16 + lr;
            float b = bias[col];
#pragma unroll
            for (int r = 0; r < 4; ++r) {
                int row = mt * 16 + (lane >> 4) * 4 + r;
                cst[row][col] = f2bf(fmaxf(acc[mt][nt][r] + b, 0.f));
            }
        }
    __syncthreads();

    // segmented pooling: thread = column, walk the 64 sorted rows
    int rows = M - m0; if (rows > 64) rows = 64;
    float s = 0.f;
    int gp = batch_s[0];
    for (int r = 0; r < rows; ++r) {
        int g = batch_s[r];
        if (g != gp) {
            atomicAdd(&pooled[(size_t)gp * H_DIM + tid], s);
            s = 0.f;
            gp = g;
        }
        s += bf2f(cst[r][tid]);
    }
    atomicAdd(&pooled[(size_t)gp * H_DIM + tid], s);
}

// ---------------------------------------------------------------------------
// Heads (fp32): h_graph = pooled/cnt (cnt from goff diffs); mu/logvar heads
// ---------------------------------------------------------------------------
__global__ void head_kernel(const float* __restrict__ pooled, const int* __restrict__ goff,
                            const float* __restrict__ Wmu, const float* __restrict__ bmu,
                            const float* __restrict__ Wlv, const float* __restrict__ blv,
                            float* __restrict__ out) {
    __shared__ float hg[H_DIM];
    int g = blockIdx.x, l = threadIdx.x;   // 64 threads
    float inv = 1.0f / fmaxf((float)(goff[g + 1] - goff[g]), 1.0f);
    for (int k = l; k < H_DIM; k += 64) hg[k] = pooled[(size_t)g * H_DIM + k] * inv;
    __syncthreads();
    float mu = bmu[l], lv = blv[l];
    for (int k = 0; k < H_DIM; ++k) {
        float h = hg[k];
        mu = fmaf(h, Wmu[k * L_DIM + l], mu);
        lv = fmaf(h, Wlv[k * L_DIM + l], lv);
    }
    out[(size_t)g * L_DIM + l] = mu;
    out[(size_t)G_NUM * L_DIM + (size_t)g * L_DIM + l] = lv;
}

// ---------------------------------------------------------------------------
extern "C" void kernel_launch(void* const* d_in, const int* in_sizes, int n_in,
                              void* d_out, int out_size, void* d_ws, size_t ws_size,
                              hipStream_t stream) {
    const float* x     = (const float*)d_in[0];
    const int*   ei    = (const int*)  d_in[1];
    const int*   batch = (const int*)  d_in[2];
    const float* W1  = (const float*)d_in[4];
    const float* b1  = (const float*)d_in[5];
    const float* W2  = (const float*)d_in[6];
    const float* b2  = (const float*)d_in[7];
    const float* Wmu = (const float*)d_in[8];
    const float* bmu = (const float*)d_in[9];
    const float* Wlv = (const float*)d_in[10];
    const float* blv = (const float*)d_in[11];
    const int* src = ei;
    const int* dst = ei + N_EDGES;

    char* ws = (char*)d_ws;
    size_t off = 0;
    auto alloc = [&](size_t bytes) -> void* {
        void* p = ws + off;
        off += (bytes + 255) & ~(size_t)255;
        return p;
    };
    // pooled + bcur adjacent -> one memset clears both
    float* pooled   = (float*)alloc((size_t)G_NUM * H_DIM * 4);
    int*   bcur     = (int*)alloc((size_t)NBUCK * CUR_STRIDE * 4);
    float* dinv     = (float*)alloc((size_t)N_NODES * 4);
    int*   row_ptr  = (int*)alloc((size_t)(N_NODES + 1) * 4);
    u32*   csr      = (u32*)alloc((size_t)N_EDGES * 4);
    u32*   binrec   = (u32*)alloc((size_t)NBUCK * BUCK_CAP * 4);  // 6.4 MB
    int*   excl     = (int*)alloc((size_t)N_NODES * 4);
    int*   partials = (int*)alloc(256 * 4);
    int*   goff     = (int*)alloc((size_t)(G_NUM + 1) * 4);
    u8*    xq    = (u8*)alloc((size_t)N_NODES * F_IN_D);       // 6.4 MB (fp8)
    u16*   Xa    = (u16*)alloc((size_t)N_NODES * F_IN_D * 2);  // 12.8 MB
    u8*    H8    = (u8*)alloc((size_t)N_NODES * H_DIM);        // 12.8 MB (fp8)
    u8*    Ha    = (u8*)alloc((size_t)N_NODES * H_DIM);        // 12.8 MB (fp8)
    u16*   w1swz = (u16*)alloc((size_t)2 * F_IN_D * H_DIM * 2);
    u16*   w2swz = (u16*)alloc((size_t)2 * H_DIM * H_DIM * 2);
    (void)ws_size; (void)n_in; (void)in_sizes; (void)out_size;

    const int GEMM_NB = (N_NODES + 63) / 64;     // 782
    size_t zero_bytes = (size_t)((char*)(bcur + NBUCK * CUR_STRIDE) - (char*)pooled);

    hipMemsetAsync(pooled, 0, zero_bytes, stream);
    prep_kernel<<<BIN_NB + NB_SCAN + NB_CONV, 256, 0, stream>>>(
        src, dst, batch, goff, x, xq, W1, w1swz, W2, w2swz, bcur, binrec);
    cnt_scan_kernel<<<NBUCK, 256, 0, stream>>>(bcur, binrec, excl, partials, dinv);
    place2_kernel<<<NBUCK, 256, 0, stream>>>(excl, partials, bcur, binrec, dinv, row_ptr, csr);

    // layer 1: aggregate(x fp8) then GEMM  (A_hat (X W) == (A_hat X) W)
    agg128_fp8_kernel<<<(N_NODES + 3) / 4, 256, 0, stream>>>(xq, dinv, row_ptr, csr, Xa);
    gemm1_kernel<F_IN_D><<<GEMM_NB, 256, 0, stream>>>(Xa, (const short8*)w1swz, b1, H8, N_NODES);
    // layer 2: aggregate(H1 fp8) -> fp8, then GEMM with fused mean-pool
    agg256_fp8_kernel<<<(N_NODES + 3) / 4, 256, 0, stream>>>(H8, dinv, row_ptr, csr, Ha);
    gemm2_pool_kernel<<<GEMM_NB, 256, 0, stream>>>(Ha, (const short8*)w2swz, b2, batch, pooled, N_NODES);

    head_kernel<<<G_NUM, 64, 0, stream>>>(pooled, goff, Wmu, bmu, Wlv, blv, (float*)d_out);
}